// Round 1
// baseline (1421.545 us; speedup 1.0000x reference)
//
#include <hip/hip_runtime.h>

#define EDGES 1000000
#define NODES 100000
#define ET 128   // edges per block-tile (4 waves x 32)
#define NB 64    // nodes per block (node_kernel)
#define NBLK ((NODES + NB - 1) / NB)  // 1563

typedef short short8 __attribute__((ext_vector_type(8)));
typedef float floatx4 __attribute__((ext_vector_type(4)));
typedef unsigned int u32x2 __attribute__((ext_vector_type(2)));

#define MFMA(a, b, c) __builtin_amdgcn_mfma_f32_16x16x32_bf16(a, b, c, 0, 0, 0)

// ws layout (bytes)
#define WS_WX1 0        // 32768: Wx1 bf16 frags
#define WS_WX2 32768    // 16384: Wx2 frags
#define WS_WP1 49152    // 16384: Wp1 frags
#define WS_MISC 65536   // 2048: biases etc (floats)
#define WS_OFF 68608    // off[100128] int = 400512 B (CSR offsets, padded)
#define WS_CNT 469504   // counts/cursor[100000] int = 400000 B (aliased)
#define WS_SREC 917504  // uint2[EDGES] = 8 MB sorted (row,col) records
// scan temporaries alias the srec region (they die before scatter writes srec):
#define WS_TMP WS_SREC                 // int[100352] inclusive per-block scans
#define WS_BSUM (WS_SREC + 401408)     // int[98] block sums
#define WS_BSUMX (WS_SREC + 402432)    // int[128] exclusive-scanned block sums

__device__ __forceinline__ unsigned short f2bf(float f) {
  union { float f; unsigned int u; } c;
  c.f = f;
  unsigned int u = c.u;
  u += 0x7fffu + ((u >> 16) & 1u);
  return (unsigned short)(u >> 16);
}

__device__ __forceinline__ unsigned int pack2bf(float lo, float hi) {
  return (unsigned int)f2bf(lo) | ((unsigned int)f2bf(hi) << 16);
}

__device__ __forceinline__ float fast_silu(float v) {
#if __has_builtin(__builtin_amdgcn_exp2f) && __has_builtin(__builtin_amdgcn_rcpf)
  float e = __builtin_amdgcn_exp2f(-1.44269504088896340736f * v);
  return v * __builtin_amdgcn_rcpf(1.0f + e);
#else
  return v / (1.0f + __expf(-v));
#endif
}

// DPP cross-lane within 16-lane rows. row_shr:N = lane i reads lane i-N;
// MUST be called unconditionally in straight-line code (convergent ops).
template <int CTRL>
__device__ __forceinline__ int dpp_i(int v) {
  return __builtin_amdgcn_update_dpp(0, v, CTRL, 0xf, 0xf, true);
}
template <int CTRL>
__device__ __forceinline__ float dpp_f(float v) {
  return __builtin_bit_cast(float, dpp_i<CTRL>(__builtin_bit_cast(int, v)));
}

// Segmented inclusive prefix-sum across nn (16-lane row), segments = runs of
// equal sorted keys; masks m1..m8 from unconditional key equality at d=1,2,4,8.
__device__ __forceinline__ float segscan(float v, bool m1, bool m2, bool m4, bool m8) {
  float t;
  t = dpp_f<0x111>(v); v += m1 ? t : 0.f;
  t = dpp_f<0x112>(v); v += m2 ? t : 0.f;
  t = dpp_f<0x114>(v); v += m4 ? t : 0.f;
  t = dpp_f<0x118>(v); v += m8 ? t : 0.f;
  return v;
}

__device__ __forceinline__ void lds_add(float* p, float v) {
  __hip_atomic_fetch_add(p, v, __ATOMIC_RELAXED, __HIP_MEMORY_SCOPE_WORKGROUP);
}

__global__ __launch_bounds__(256) void prep_kernel(
    const float* __restrict__ Wx1, const float* __restrict__ Wx2,
    const float* __restrict__ Wp1, const float* __restrict__ bx1,
    const float* __restrict__ bx2, const float* __restrict__ bp1,
    const float* __restrict__ Wp2, const float* __restrict__ bp2,
    unsigned char* __restrict__ ws) {
  const int t = blockIdx.x * 256 + threadIdx.x;
  const int nthr = gridDim.x * 256;

  for (int task = t; task < 2048; task += nthr) {  // Wx1[0:128][0:128]
    const int n = task & 127;
    const int kb = task >> 7;
    const int k0 = kb << 3;
    unsigned int d[4];
#pragma unroll
    for (int i = 0; i < 4; ++i)
      d[i] = pack2bf(Wx1[(k0 + 2 * i) * 128 + n], Wx1[(k0 + 2 * i + 1) * 128 + n]);
    const int lane = ((kb & 3) << 4) | (n & 15);
    const int frag = ((kb >> 2) << 3) | (n >> 4);
    *(uint4*)(ws + WS_WX1 + ((size_t)(frag * 64 + lane) << 4)) =
        make_uint4(d[0], d[1], d[2], d[3]);
  }
  for (int task = t; task < 1024; task += nthr) {  // Wx2[0:128][0:64]
    const int n = task & 63;
    const int kb = task >> 6;
    const int k0 = kb << 3;
    unsigned int d[4];
#pragma unroll
    for (int i = 0; i < 4; ++i)
      d[i] = pack2bf(Wx2[(k0 + 2 * i) * 64 + n], Wx2[(k0 + 2 * i + 1) * 64 + n]);
    const int lane = ((kb & 3) << 4) | (n & 15);
    const int frag = ((kb >> 2) << 2) | (n >> 4);
    *(uint4*)(ws + WS_WX2 + ((size_t)(frag * 64 + lane) << 4)) =
        make_uint4(d[0], d[1], d[2], d[3]);
  }
  for (int task = t; task < 1024; task += nthr) {  // Wp1[0:64][0:128]
    const int n = task & 127;
    const int kb = task >> 7;
    const int k0 = kb << 3;
    unsigned int d[4];
#pragma unroll
    for (int i = 0; i < 4; ++i)
      d[i] = pack2bf(Wp1[(k0 + 2 * i) * 128 + n], Wp1[(k0 + 2 * i + 1) * 128 + n]);
    const int lane = ((kb & 3) << 4) | (n & 15);
    const int frag = ((kb >> 2) << 3) | (n >> 4);
    *(uint4*)(ws + WS_WP1 + ((size_t)(frag * 64 + lane) << 4)) =
        make_uint4(d[0], d[1], d[2], d[3]);
  }
  float* misc = (float*)(ws + WS_MISC);
  for (int i = t; i < 128; i += nthr) misc[i] = bx1[i];
  for (int i = t; i < 64; i += nthr) misc[128 + i] = bx2[i];
  for (int i = t; i < 128; i += nthr) misc[192 + i] = bp1[i];
  for (int i = t; i < 128; i += nthr) misc[320 + i] = Wp2[i];
  if (t == 0) misc[448] = bp2[0];
  for (int i = t; i < 128; i += nthr) misc[456 + i] = Wx1[128 * 128 + i];
}

// ---- counting sort by col ----
__global__ __launch_bounds__(256) void hist_kernel(const int* __restrict__ ei,
                                                   int* __restrict__ counts) {
  const int t = blockIdx.x * 256 + threadIdx.x;
  if (t < EDGES) {
    int c = __builtin_nontemporal_load(ei + EDGES + t);
    c = (c < 0) ? 0 : ((c >= NODES) ? NODES - 1 : c);
    atomicAdd(&counts[c], 1);
  }
}

#define SCB 98  // blocks of 1024: 98*1024 = 100352 >= NODES+128

__global__ __launch_bounds__(1024) void scan1_kernel(const int* __restrict__ counts,
                                                     int* __restrict__ tmp,
                                                     int* __restrict__ bsum) {
  __shared__ int part[1024];
  const int t = threadIdx.x;
  const int i = blockIdx.x * 1024 + t;
  int v = (i < NODES) ? counts[i] : 0;
  part[t] = v;
  __syncthreads();
  for (int d = 1; d < 1024; d <<= 1) {
    int u = 0;
    if (t >= d) u = part[t - d];
    __syncthreads();
    if (t >= d) part[t] += u;
    __syncthreads();
  }
  tmp[i] = part[t];  // inclusive scan within block
  if (t == 1023) bsum[blockIdx.x] = part[1023];
}

__global__ __launch_bounds__(128) void scan2_kernel(const int* __restrict__ bsum,
                                                    int* __restrict__ bsumx) {
  __shared__ int part[128];
  const int t = threadIdx.x;
  int v = (t < SCB) ? bsum[t] : 0;
  part[t] = v;
  __syncthreads();
  for (int d = 1; d < 128; d <<= 1) {
    int u = 0;
    if (t >= d) u = part[t - d];
    __syncthreads();
    if (t >= d) part[t] += u;
    __syncthreads();
  }
  bsumx[t] = part[t] - v;  // exclusive
}

__global__ __launch_bounds__(1024) void scan3_kernel(const int* __restrict__ counts,
                                                     const int* __restrict__ tmp,
                                                     const int* __restrict__ bsumx,
                                                     int* __restrict__ off,
                                                     int* __restrict__ cursor) {
  const int i = blockIdx.x * 1024 + threadIdx.x;
  if (i < NODES) {
    const int cn = counts[i];  // read before cursor write (aliased with counts)
    const int o = bsumx[blockIdx.x] + tmp[i] - cn;
    off[i] = o;
    cursor[i] = o;
  } else if (i < NODES + 128) {
    off[i] = EDGES;
  }
}

__global__ __launch_bounds__(256) void scatter_kernel(const int* __restrict__ ei,
                                                      int* __restrict__ cursor,
                                                      unsigned int* __restrict__ srec) {
  const int t = blockIdx.x * 256 + threadIdx.x;
  if (t < EDGES) {
    int r = __builtin_nontemporal_load(ei + t);
    int c = __builtin_nontemporal_load(ei + EDGES + t);
    r = (r < 0) ? 0 : ((r >= NODES) ? NODES - 1 : r);
    c = (c < 0) ? 0 : ((c >= NODES) ? NODES - 1 : c);
    const int p = atomicAdd(&cursor[c], 1);
    srec[2 * (size_t)p] = (unsigned)r;
    srec[2 * (size_t)p + 1] = (unsigned)c;
  }
}

// ---- main: node-centric, zero global atomics ----
// R10: barrier-free per-wave pipeline. Audit showed sFeat was already
// wave-private (wave w touches frag rows 8w..8w+7 only) and sLC/sRel/sDist
// were cross-wave ONLY because phase A assigned edges by tid. Now each wave
// owns its 32-edge micro-tile end-to-end: it prefetches srec/pos/x-gathers
// into REGISTERS (packed bf16) during the previous tile's GEMMs (T14
// issue-early/write-late), writes them to wave-private LDS, and runs the
// GEMMs — with ZERO in-loop __syncthreads (no vmcnt/lgkmcnt drains).
// Cross-wave communication is only the LDS-atomic sAccX accumulate.
// sRowE deleted: gather addresses come straight from srec (L1-hot broadcast).
__global__ __launch_bounds__(256, 3) void node_kernel(
    const float* __restrict__ x, const float* __restrict__ pos,
    const unsigned char* __restrict__ ws, float* __restrict__ out) {
  __shared__ uint4 sFeat[2048];                    // 32 KB B-operand frags (wave-private rows)
  __shared__ __align__(16) float sAccX[NB * 68];   // 17 KB; cols 64..66 = pos acc
  __shared__ float sRel[ET * 3];                   // wave-private slices [32w,32w+32)
  __shared__ float sDist[ET];
  __shared__ int sLC[ET];

  const int tid = threadIdx.x;
  const int lane = tid & 63;
  const int wave = tid >> 6;
  const int q = lane >> 4;
  const int nn = lane & 15;
  const int base = blockIdx.x * NB;
  const int et0 = wave * 2;
  const int W32 = wave * 32;

  const int* off = (const int*)(ws + WS_OFF);
  const unsigned int* srec = (const unsigned int*)(ws + WS_SREC);
  const uint4* wx1f = (const uint4*)(ws + WS_WX1);
  const uint4* wx2f = (const uint4*)(ws + WS_WX2);
  const uint4* wp1f = (const uint4*)(ws + WS_WP1);
  const float* misc = (const float*)(ws + WS_MISC);

  const int e0 = off[base];
  const int e1 = off[base + NB];

  for (int i = tid; i < NB * 68; i += 256) sAccX[i] = 0.f;
  __syncthreads();  // sAccX ready before any LDS-atomic adds

  const floatx4 fzero = {0.f, 0.f, 0.f, 0.f};

  // prefetch state (tile currently in registers, not yet in LDS)
  u32x2 pk[16];                       // packed bf16 x-frags (8B each)
  float nr0 = 0.f, nr1 = 0.f, nr2 = 0.f, ndist = 0.f;
  int nlc = 0;

  const int t0w = e0 + W32;  // this wave's first micro-tile (stride 128)

  if (t0w < e1) {  // prologue: full prefetch of first tile
    unsigned int nodeg[16];
    u32x2 rcE;
    {
      int e = t0w + (lane & 31);
      e = e < EDGES ? e : EDGES - 1;
      rcE = *(const u32x2*)(srec + 2 * (size_t)e);
#pragma unroll
      for (int i = 0; i < 8; ++i) {
        int eg = t0w + i * 4 + (lane >> 4);
        eg = eg < EDGES ? eg : EDGES - 1;
        const u32x2 rc = *(const u32x2*)(srec + 2 * (size_t)eg);
        nodeg[i] = rc[0];      // rows -> halves 0
        nodeg[8 + i] = rc[1];  // cols -> halves 1
      }
    }
    float4 xv[8];
#pragma unroll
    for (int i = 0; i < 8; ++i)
      xv[i] = *(const float4*)(x + (size_t)nodeg[i] * 64 + (lane & 15) * 4);
#pragma unroll
    for (int i = 0; i < 8; ++i) {
      pk[i][0] = pack2bf(xv[i].x, xv[i].y);
      pk[i][1] = pack2bf(xv[i].z, xv[i].w);
    }
#pragma unroll
    for (int i = 0; i < 8; ++i)
      xv[i] = *(const float4*)(x + (size_t)nodeg[8 + i] * 64 + (lane & 15) * 4);
#pragma unroll
    for (int i = 0; i < 8; ++i) {
      pk[8 + i][0] = pack2bf(xv[i].x, xv[i].y);
      pk[8 + i][1] = pack2bf(xv[i].z, xv[i].w);
    }
    const int r = (int)rcE[0], c = (int)rcE[1];
    const float ax = pos[3 * r + 0], ay = pos[3 * r + 1], az = pos[3 * r + 2];
    const float cx = pos[3 * c + 0], cy = pos[3 * c + 1], cz = pos[3 * c + 2];
    nr0 = ax - cx; nr1 = ay - cy; nr2 = az - cz;
    ndist = nr0 * nr0 + nr1 * nr1 + nr2 * nr2;
    int l = c - base;
    l = (l < 0) ? 0 : ((l > NB - 1) ? NB - 1 : l);
    nlc = l;
  }

#pragma unroll 1
  for (int t = t0w; t < e1; t += 128) {
    // ---- A: drain prefetched tile into wave-private LDS (in-order DS pipe
    // orders these vs this wave's later ds_reads; no barrier needed)
#pragma unroll
    for (int it = 0; it < 16; ++it) {
      const int sl = (it & 7) * 4 + (lane >> 4);  // slot 0..31 within wave
      const int kq = lane & 15;
      const int s = W32 + sl;
      const int kt = ((it >> 3) << 1) | (kq >> 3);
      const int fl = (((kq >> 1) & 3) << 4) | (s & 15);
      *((u32x2*)&sFeat[((s >> 4) * 4 + kt) * 64 + fl] + (kq & 1)) = pk[it];
    }
    if (lane < 32) {
      const int j = W32 + lane;
      sLC[j] = nlc;
      sDist[j] = ndist;
      sRel[3 * j + 0] = nr0;
      sRel[3 * j + 1] = nr1;
      sRel[3 * j + 2] = nr2;
    }

    // ---- B: issue next-tile srec loads (sequential, L1-hot)
    const int tn = t + 128;
    const bool pf = tn < e1;
    unsigned int nodeg[16];
    u32x2 rcE;
    if (pf) {
      int e = tn + (lane & 31);
      e = e < EDGES ? e : EDGES - 1;
      rcE = *(const u32x2*)(srec + 2 * (size_t)e);
#pragma unroll
      for (int i = 0; i < 8; ++i) {
        int eg = tn + i * 4 + (lane >> 4);
        eg = eg < EDGES ? eg : EDGES - 1;
        const u32x2 rc = *(const u32x2*)(srec + 2 * (size_t)eg);
        nodeg[i] = rc[0];
        nodeg[8 + i] = rc[1];
      }
    }

    // ---- C: phi_pos (mm-paired, kt unroll 1) + segmented-scan scatter
    {
      floatx4 accp[2][8];
#pragma unroll
      for (int m = 0; m < 2; ++m)
#pragma unroll
        for (int j = 0; j < 8; ++j) accp[m][j] = fzero;
#pragma unroll 1
      for (int kt = 0; kt < 2; ++kt) {  // x_row occupies k 0..63
        const short8 b0 = __builtin_bit_cast(short8, sFeat[((et0 + 0) * 4 + kt) * 64 + lane]);
        const short8 b1 = __builtin_bit_cast(short8, sFeat[((et0 + 1) * 4 + kt) * 64 + lane]);
#pragma unroll
        for (int jt = 0; jt < 8; ++jt) {
          const short8 a = __builtin_bit_cast(short8, wp1f[(kt * 8 + jt) * 64 + lane]);
          accp[0][jt] = MFMA(a, b0, accp[0][jt]);
          accp[1][jt] = MFMA(a, b1, accp[1][jt]);
        }
      }
#pragma unroll
      for (int m = 0; m < 2; ++m) {
        float s = 0.f;
#pragma unroll
        for (int jt = 0; jt < 8; ++jt) {
          const float4 bp = *(const float4*)(misc + 192 + jt * 16 + q * 4);
          const float4 wp = *(const float4*)(misc + 320 + jt * 16 + q * 4);
          s += fast_silu(accp[m][jt][0] + bp.x) * wp.x;
          s += fast_silu(accp[m][jt][1] + bp.y) * wp.y;
          s += fast_silu(accp[m][jt][2] + bp.z) * wp.z;
          s += fast_silu(accp[m][jt][3] + bp.w) * wp.w;
        }
        s += __shfl_xor(s, 16);
        s += __shfl_xor(s, 32);
        const float wv = s + misc[448];  // all 64 lanes hold per-nn value

        const int el = (et0 + m) * 16 + nn;
        const bool vE = (t + m * 16 + nn) < e1;
        int lcv = sLC[el];
        if (!vE) lcv = -1 - nn;  // singleton segments for invalid lanes
        // unconditional DPPs (convergent!) then bitwise combines:
        const int k1 = dpp_i<0x111>(lcv);
        const int k2 = dpp_i<0x112>(lcv);
        const int k4 = dpp_i<0x114>(lcv);
        const int k8 = dpp_i<0x118>(lcv);
        const int kn = dpp_i<0x101>(lcv);
        const bool m1 = (nn >= 1) & (k1 == lcv);
        const bool m2 = (nn >= 2) & (k2 == lcv);
        const bool m4 = (nn >= 4) & (k4 == lcv);
        const bool m8 = (nn >= 8) & (k8 == lcv);
        const bool tail = vE & ((nn == 15) | (kn != lcv));

        float p0 = segscan(wv * sRel[3 * el + 0], m1, m2, m4, m8);
        float p1 = segscan(wv * sRel[3 * el + 1], m1, m2, m4, m8);
        float p2 = segscan(wv * sRel[3 * el + 2], m1, m2, m4, m8);
        if (tail && q == 0) {
          float* ap = sAccX + lcv * 68 + 64;  // pos acc lives in the pad
          lds_add(ap + 0, p0);
          lds_add(ap + 1, p1);
          lds_add(ap + 2, p2);
        }
      }
    }

    // ---- D: issue next-tile pos loads + half-0 x-gathers (hide under GEMM1)
    float prx = 0.f, pry = 0.f, prz = 0.f, pcx = 0.f, pcy = 0.f, pcz = 0.f;
    float4 xv0[8];
    if (pf) {
      const int r = (int)rcE[0], c = (int)rcE[1];
      prx = pos[3 * r + 0]; pry = pos[3 * r + 1]; prz = pos[3 * r + 2];
      pcx = pos[3 * c + 0]; pcy = pos[3 * c + 1]; pcz = pos[3 * c + 2];
#pragma unroll
      for (int i = 0; i < 8; ++i)
        xv0[i] = *(const float4*)(x + (size_t)nodeg[i] * 64 + (lane & 15) * 4);
    }

    // ---- E: GEMM1 (mm-paired) + epilogue 1
    {
      floatx4 acc1[2][8];
#pragma unroll
      for (int m = 0; m < 2; ++m)
#pragma unroll
        for (int j = 0; j < 8; ++j) acc1[m][j] = fzero;
#pragma unroll 1
      for (int kt = 0; kt < 4; ++kt) {
        const short8 b0 = __builtin_bit_cast(short8, sFeat[((et0 + 0) * 4 + kt) * 64 + lane]);
        const short8 b1 = __builtin_bit_cast(short8, sFeat[((et0 + 1) * 4 + kt) * 64 + lane]);
#pragma unroll
        for (int jt = 0; jt < 8; ++jt) {
          const short8 a = __builtin_bit_cast(short8, wx1f[(kt * 8 + jt) * 64 + lane]);
          acc1[0][jt] = MFMA(a, b0, acc1[0][jt]);
          acc1[1][jt] = MFMA(a, b1, acc1[1][jt]);
        }
      }
#pragma unroll
      for (int m = 0; m < 2; ++m) {
        const int etG = et0 + m;
        const float dist = sDist[etG * 16 + nn];
#pragma unroll
        for (int jt = 0; jt < 8; ++jt) {
          const float4 bx = *(const float4*)(misc + 0 + jt * 16 + q * 4);
          const float4 wd = *(const float4*)(misc + 456 + jt * 16 + q * 4);
          const unsigned int h01 = pack2bf(fast_silu(acc1[m][jt][0] + bx.x + dist * wd.x),
                                           fast_silu(acc1[m][jt][1] + bx.y + dist * wd.y));
          const unsigned int h23 = pack2bf(fast_silu(acc1[m][jt][2] + bx.z + dist * wd.z),
                                           fast_silu(acc1[m][jt][3] + bx.w + dist * wd.w));
          const int j0 = jt * 16 + q * 4;
          const int kt2 = j0 >> 5;
          const int lane2 = (((j0 & 31) >> 3) << 4) | nn;
          const int byteoff = (j0 & 7) << 1;
          uint2* dst = (uint2*)((char*)sFeat +
                                (((size_t)((etG * 4 + kt2) * 64 + lane2)) << 4) + byteoff);
          *dst = make_uint2(h01, h23);
        }
      }
    }

    // ---- F: pack half-0, issue half-1 x-gathers (hide under GEMM2)
    float4 xv1[8];
    if (pf) {
#pragma unroll
      for (int i = 0; i < 8; ++i) {
        pk[i][0] = pack2bf(xv0[i].x, xv0[i].y);
        pk[i][1] = pack2bf(xv0[i].z, xv0[i].w);
      }
#pragma unroll
      for (int i = 0; i < 8; ++i)
        xv1[i] = *(const float4*)(x + (size_t)nodeg[8 + i] * 64 + (lane & 15) * 4);
    }

    // ---- G: GEMM2 (mm-paired) + segmented-scan scatter epilogue
    {
      floatx4 acc2[2][4];
#pragma unroll
      for (int m = 0; m < 2; ++m)
#pragma unroll
        for (int it = 0; it < 4; ++it) acc2[m][it] = fzero;
#pragma unroll 1
      for (int kt = 0; kt < 4; ++kt) {
        const short8 b0 = __builtin_bit_cast(short8, sFeat[((et0 + 0) * 4 + kt) * 64 + lane]);
        const short8 b1 = __builtin_bit_cast(short8, sFeat[((et0 + 1) * 4 + kt) * 64 + lane]);
#pragma unroll
        for (int it = 0; it < 4; ++it) {
          const short8 a = __builtin_bit_cast(short8, wx2f[(kt * 4 + it) * 64 + lane]);
          acc2[0][it] = MFMA(a, b0, acc2[0][it]);
          acc2[1][it] = MFMA(a, b1, acc2[1][it]);
        }
      }
#pragma unroll
      for (int m = 0; m < 2; ++m) {
        const int el = (et0 + m) * 16 + nn;
        const bool vE = (t + m * 16 + nn) < e1;
        int lcv = sLC[el];
        if (!vE) lcv = -1 - nn;
        const int k1 = dpp_i<0x111>(lcv);
        const int k2 = dpp_i<0x112>(lcv);
        const int k4 = dpp_i<0x114>(lcv);
        const int k8 = dpp_i<0x118>(lcv);
        const int kn = dpp_i<0x101>(lcv);
        const bool m1 = (nn >= 1) & (k1 == lcv);
        const bool m2 = (nn >= 2) & (k2 == lcv);
        const bool m4 = (nn >= 4) & (k4 == lcv);
        const bool m8 = (nn >= 8) & (k8 == lcv);
        const bool tail = vE & ((nn == 15) | (kn != lcv));
#pragma unroll
        for (int it = 0; it < 4; ++it) {
          const float4 b2 = *(const float4*)(misc + 128 + it * 16 + q * 4);
          float v0 = segscan(acc2[m][it][0] + b2.x, m1, m2, m4, m8);
          float v1 = segscan(acc2[m][it][1] + b2.y, m1, m2, m4, m8);
          float v2 = segscan(acc2[m][it][2] + b2.z, m1, m2, m4, m8);
          float v3 = segscan(acc2[m][it][3] + b2.w, m1, m2, m4, m8);
          if (tail) {
            float* arow = sAccX + lcv * 68;
            const int i0 = it * 16 + q * 4;
            lds_add(arow + i0 + 0, v0);
            lds_add(arow + i0 + 1, v1);
            lds_add(arow + i0 + 2, v2);
            lds_add(arow + i0 + 3, v3);
          }
        }
      }
    }

    // ---- H: pack half-1, finish next-tile edge data (rel/dist/lc)
    if (pf) {
#pragma unroll
      for (int i = 0; i < 8; ++i) {
        pk[8 + i][0] = pack2bf(xv1[i].x, xv1[i].y);
        pk[8 + i][1] = pack2bf(xv1[i].z, xv1[i].w);
      }
      nr0 = prx - pcx; nr1 = pry - pcy; nr2 = prz - pcz;
      ndist = nr0 * nr0 + nr1 * nr1 + nr2 * nr2;
      int l = (int)rcE[1] - base;
      l = (l < 0) ? 0 : ((l > NB - 1) ? NB - 1 : l);
      nlc = l;
    }
  }
  __syncthreads();  // all waves' LDS-atomic accumulates done

  // ---- final coalesced stores (no global atomics)
  {
    const int n = base + (tid >> 2);
    if (n < NODES) {
      const int c0 = (tid & 3) * 16;
      float* orow = out + (size_t)n * 64 + c0;
      const float* arow = sAccX + (tid >> 2) * 68 + c0;
#pragma unroll
      for (int j = 0; j < 16; j += 4) *(float4*)(orow + j) = *(const float4*)(arow + j);
    }
    if (tid < 192) {
      const int idx = base * 3 + tid;
      if (idx < NODES * 3)
        out[(size_t)NODES * 64 + idx] = sAccX[(tid / 3) * 68 + 64 + (tid % 3)];
    }
  }
}

extern "C" void kernel_launch(void* const* d_in, const int* in_sizes, int n_in,
                              void* d_out, int out_size, void* d_ws, size_t ws_size,
                              hipStream_t stream) {
  (void)in_sizes; (void)n_in; (void)ws_size; (void)out_size;
  const float* x = (const float*)d_in[0];
  const float* pos = (const float*)d_in[1];
  const int* ei = (const int*)d_in[2];
  const float* Wx1 = (const float*)d_in[3];
  const float* bx1 = (const float*)d_in[4];
  const float* Wx2 = (const float*)d_in[5];
  const float* bx2 = (const float*)d_in[6];
  const float* Wp1 = (const float*)d_in[7];
  const float* bp1 = (const float*)d_in[8];
  const float* Wp2 = (const float*)d_in[9];
  const float* bp2 = (const float*)d_in[10];
  float* out = (float*)d_out;
  unsigned char* ws = (unsigned char*)d_ws;

  int* counts = (int*)(ws + WS_CNT);   // aliased with cursor (scan3 rewrites)
  int* cursor = (int*)(ws + WS_CNT);
  int* off = (int*)(ws + WS_OFF);
  int* tmp = (int*)(ws + WS_TMP);      // aliased with srec (dies before scatter)
  int* bsum = (int*)(ws + WS_BSUM);
  int* bsumx = (int*)(ws + WS_BSUMX);
  unsigned int* srec = (unsigned int*)(ws + WS_SREC);

  hipMemsetAsync(counts, 0, (size_t)NODES * sizeof(int), stream);
  prep_kernel<<<16, 256, 0, stream>>>(Wx1, Wx2, Wp1, bx1, bx2, bp1, Wp2, bp2, ws);
  const int eb = (EDGES + 255) / 256;
  hist_kernel<<<eb, 256, 0, stream>>>(ei, counts);
  scan1_kernel<<<SCB, 1024, 0, stream>>>(counts, tmp, bsum);
  scan2_kernel<<<1, 128, 0, stream>>>(bsum, bsumx);
  scan3_kernel<<<SCB, 1024, 0, stream>>>(counts, tmp, bsumx, off, cursor);
  scatter_kernel<<<eb, 256, 0, stream>>>(ei, cursor, srec);
  node_kernel<<<NBLK, 256, 0, stream>>>(x, pos, ws, out);
}

// Round 2
// 800.846 us; speedup vs baseline: 1.7751x; 1.7751x over previous
//
#include <hip/hip_runtime.h>

#define EDGES 1000000
#define NODES 100000
#define ET 128   // edges per tile
#define NB 64    // nodes per block (node_kernel)
#define NBLK ((NODES + NB - 1) / NB)  // 1563

typedef short short8 __attribute__((ext_vector_type(8)));
typedef float floatx4 __attribute__((ext_vector_type(4)));
typedef unsigned int u32x2 __attribute__((ext_vector_type(2)));

#define MFMA(a, b, c) __builtin_amdgcn_mfma_f32_16x16x32_bf16(a, b, c, 0, 0, 0)

// ws layout (bytes)
#define WS_WX1 0        // 32768: Wx1 bf16 frags
#define WS_WX2 32768    // 16384: Wx2 frags
#define WS_WP1 49152    // 16384: Wp1 frags
#define WS_MISC 65536   // 2048: biases etc (floats)
#define WS_OFF 68608    // off[100128] int = 400512 B (CSR offsets, padded)
#define WS_CNT 469504   // counts/cursor[100000] int = 400000 B (aliased)
#define WS_SREC 917504  // uint2[EDGES] = 8 MB sorted (row,col) records
// scan temporaries alias the srec region (they die before scatter writes srec):
#define WS_TMP WS_SREC                 // int[100352] inclusive per-block scans
#define WS_BSUM (WS_SREC + 401408)     // int[98] block sums
#define WS_BSUMX (WS_SREC + 402432)    // int[128] exclusive-scanned block sums

__device__ __forceinline__ unsigned short f2bf(float f) {
  union { float f; unsigned int u; } c;
  c.f = f;
  unsigned int u = c.u;
  u += 0x7fffu + ((u >> 16) & 1u);
  return (unsigned short)(u >> 16);
}

__device__ __forceinline__ unsigned int pack2bf(float lo, float hi) {
  return (unsigned int)f2bf(lo) | ((unsigned int)f2bf(hi) << 16);
}

__device__ __forceinline__ float fast_silu(float v) {
#if __has_builtin(__builtin_amdgcn_exp2f) && __has_builtin(__builtin_amdgcn_rcpf)
  float e = __builtin_amdgcn_exp2f(-1.44269504088896340736f * v);
  return v * __builtin_amdgcn_rcpf(1.0f + e);
#else
  return v / (1.0f + __expf(-v));
#endif
}

// DPP cross-lane within 16-lane rows. row_shr:N = lane i reads lane i-N;
// row_shl:1 = lane i reads lane i+1. MUST be called unconditionally in
// straight-line code: these are convergent ops — R8 put them behind
// &&/|| short-circuits, which masked EXEC and corrupted boundary lanes.
template <int CTRL>
__device__ __forceinline__ int dpp_i(int v) {
  return __builtin_amdgcn_update_dpp(0, v, CTRL, 0xf, 0xf, true);
}
template <int CTRL>
__device__ __forceinline__ float dpp_f(float v) {
  return __builtin_bit_cast(float, dpp_i<CTRL>(__builtin_bit_cast(int, v)));
}

// Segmented inclusive prefix-sum across nn (16-lane row), segments = runs of
// equal sorted keys; masks m1..m8 from unconditional key equality at d=1,2,4,8.
__device__ __forceinline__ float segscan(float v, bool m1, bool m2, bool m4, bool m8) {
  float t;
  t = dpp_f<0x111>(v); v += m1 ? t : 0.f;
  t = dpp_f<0x112>(v); v += m2 ? t : 0.f;
  t = dpp_f<0x114>(v); v += m4 ? t : 0.f;
  t = dpp_f<0x118>(v); v += m8 ? t : 0.f;
  return v;
}

__device__ __forceinline__ void lds_add(float* p, float v) {
  __hip_atomic_fetch_add(p, v, __ATOMIC_RELAXED, __HIP_MEMORY_SCOPE_WORKGROUP);
}

__global__ __launch_bounds__(256) void prep_kernel(
    const float* __restrict__ Wx1, const float* __restrict__ Wx2,
    const float* __restrict__ Wp1, const float* __restrict__ bx1,
    const float* __restrict__ bx2, const float* __restrict__ bp1,
    const float* __restrict__ Wp2, const float* __restrict__ bp2,
    unsigned char* __restrict__ ws) {
  const int t = blockIdx.x * 256 + threadIdx.x;
  const int nthr = gridDim.x * 256;

  for (int task = t; task < 2048; task += nthr) {  // Wx1[0:128][0:128]
    const int n = task & 127;
    const int kb = task >> 7;
    const int k0 = kb << 3;
    unsigned int d[4];
#pragma unroll
    for (int i = 0; i < 4; ++i)
      d[i] = pack2bf(Wx1[(k0 + 2 * i) * 128 + n], Wx1[(k0 + 2 * i + 1) * 128 + n]);
    const int lane = ((kb & 3) << 4) | (n & 15);
    const int frag = ((kb >> 2) << 3) | (n >> 4);
    *(uint4*)(ws + WS_WX1 + ((size_t)(frag * 64 + lane) << 4)) =
        make_uint4(d[0], d[1], d[2], d[3]);
  }
  for (int task = t; task < 1024; task += nthr) {  // Wx2[0:128][0:64]
    const int n = task & 63;
    const int kb = task >> 6;
    const int k0 = kb << 3;
    unsigned int d[4];
#pragma unroll
    for (int i = 0; i < 4; ++i)
      d[i] = pack2bf(Wx2[(k0 + 2 * i) * 64 + n], Wx2[(k0 + 2 * i + 1) * 64 + n]);
    const int lane = ((kb & 3) << 4) | (n & 15);
    const int frag = ((kb >> 2) << 2) | (n >> 4);
    *(uint4*)(ws + WS_WX2 + ((size_t)(frag * 64 + lane) << 4)) =
        make_uint4(d[0], d[1], d[2], d[3]);
  }
  for (int task = t; task < 1024; task += nthr) {  // Wp1[0:64][0:128]
    const int n = task & 127;
    const int kb = task >> 7;
    const int k0 = kb << 3;
    unsigned int d[4];
#pragma unroll
    for (int i = 0; i < 4; ++i)
      d[i] = pack2bf(Wp1[(k0 + 2 * i) * 128 + n], Wp1[(k0 + 2 * i + 1) * 128 + n]);
    const int lane = ((kb & 3) << 4) | (n & 15);
    const int frag = ((kb >> 2) << 3) | (n >> 4);
    *(uint4*)(ws + WS_WP1 + ((size_t)(frag * 64 + lane) << 4)) =
        make_uint4(d[0], d[1], d[2], d[3]);
  }
  float* misc = (float*)(ws + WS_MISC);
  for (int i = t; i < 128; i += nthr) misc[i] = bx1[i];
  for (int i = t; i < 64; i += nthr) misc[128 + i] = bx2[i];
  for (int i = t; i < 128; i += nthr) misc[192 + i] = bp1[i];
  for (int i = t; i < 128; i += nthr) misc[320 + i] = Wp2[i];
  if (t == 0) misc[448] = bp2[0];
  for (int i = t; i < 128; i += nthr) misc[456 + i] = Wx1[128 * 128 + i];
}

// ---- counting sort by col ----
__global__ __launch_bounds__(256) void hist_kernel(const int* __restrict__ ei,
                                                   int* __restrict__ counts) {
  const int t = blockIdx.x * 256 + threadIdx.x;
  if (t < EDGES) {
    int c = __builtin_nontemporal_load(ei + EDGES + t);
    c = (c < 0) ? 0 : ((c >= NODES) ? NODES - 1 : c);
    atomicAdd(&counts[c], 1);
  }
}

#define SCB 98  // blocks of 1024: 98*1024 = 100352 >= NODES+128

__global__ __launch_bounds__(1024) void scan1_kernel(const int* __restrict__ counts,
                                                     int* __restrict__ tmp,
                                                     int* __restrict__ bsum) {
  __shared__ int part[1024];
  const int t = threadIdx.x;
  const int i = blockIdx.x * 1024 + t;
  int v = (i < NODES) ? counts[i] : 0;
  part[t] = v;
  __syncthreads();
  for (int d = 1; d < 1024; d <<= 1) {
    int u = 0;
    if (t >= d) u = part[t - d];
    __syncthreads();
    if (t >= d) part[t] += u;
    __syncthreads();
  }
  tmp[i] = part[t];  // inclusive scan within block
  if (t == 1023) bsum[blockIdx.x] = part[1023];
}

__global__ __launch_bounds__(128) void scan2_kernel(const int* __restrict__ bsum,
                                                    int* __restrict__ bsumx) {
  __shared__ int part[128];
  const int t = threadIdx.x;
  int v = (t < SCB) ? bsum[t] : 0;
  part[t] = v;
  __syncthreads();
  for (int d = 1; d < 128; d <<= 1) {
    int u = 0;
    if (t >= d) u = part[t - d];
    __syncthreads();
    if (t >= d) part[t] += u;
    __syncthreads();
  }
  bsumx[t] = part[t] - v;  // exclusive
}

__global__ __launch_bounds__(1024) void scan3_kernel(const int* __restrict__ counts,
                                                     const int* __restrict__ tmp,
                                                     const int* __restrict__ bsumx,
                                                     int* __restrict__ off,
                                                     int* __restrict__ cursor) {
  const int i = blockIdx.x * 1024 + threadIdx.x;
  if (i < NODES) {
    const int cn = counts[i];  // read before cursor write (aliased with counts)
    const int o = bsumx[blockIdx.x] + tmp[i] - cn;
    off[i] = o;
    cursor[i] = o;
  } else if (i < NODES + 128) {
    off[i] = EDGES;
  }
}

__global__ __launch_bounds__(256) void scatter_kernel(const int* __restrict__ ei,
                                                      int* __restrict__ cursor,
                                                      unsigned int* __restrict__ srec) {
  const int t = blockIdx.x * 256 + threadIdx.x;
  if (t < EDGES) {
    int r = __builtin_nontemporal_load(ei + t);
    int c = __builtin_nontemporal_load(ei + EDGES + t);
    r = (r < 0) ? 0 : ((r >= NODES) ? NODES - 1 : r);
    c = (c < 0) ? 0 : ((c >= NODES) ? NODES - 1 : c);
    const int p = atomicAdd(&cursor[c], 1);
    srec[2 * (size_t)p] = (unsigned)r;
    srec[2 * (size_t)p + 1] = (unsigned)c;
  }
}

// ---- main: node-centric, zero global atomics ----
// R11: back to the R9 barrier skeleton (R10's deep register pipeline spilled
// to scratch: WRITE_SIZE 259MB -> 1.36GB). Three low-register-cost fixes:
// (a) phase-B inner loop fully unrolled: 8 gathers in flight instead of 16
//     serial latencies (v[8]=32 VGPR transient; no accumulators live there);
// (b) 1-deep prefetch of edge METADATA only (~8 VGPR: srec rec + 6 pos
//     floats); srec issued after B (hides under phi_pos), pos issued after
//     phi_pos (hides under GEMM1/2); phase A becomes pure LDS writes;
// (c) post-B barrier removed — sFeat is wave-private (wave w touches frag
//     rows 8w..8w+7 only), sLC/sRel/sDist reads are covered by the A-barrier,
//     the end-of-loop barrier protects the next tile's overwrite.
// kt loops stay unroll(1) (anti-spill, r3-r5 lesson).
__global__ __launch_bounds__(256, 3) void node_kernel(
    const float* __restrict__ x, const float* __restrict__ pos,
    const unsigned char* __restrict__ ws, float* __restrict__ out) {
  __shared__ uint4 sFeat[2048];                    // 32 KB B-operand frags
  __shared__ __align__(16) float sAccX[NB * 68];   // 17 KB; cols 64..66 = pos acc
  __shared__ float sRel[ET * 3];
  __shared__ float sDist[ET];
  __shared__ int sLC[ET];
  __shared__ int sRowE[ET];

  const int tid = threadIdx.x;
  const int lane = tid & 63;
  const int wave = tid >> 6;
  const int q = lane >> 4;
  const int nn = lane & 15;
  const int base = blockIdx.x * NB;

  const int* off = (const int*)(ws + WS_OFF);
  const unsigned int* srec = (const unsigned int*)(ws + WS_SREC);
  const uint4* wx1f = (const uint4*)(ws + WS_WX1);
  const uint4* wx2f = (const uint4*)(ws + WS_WX2);
  const uint4* wp1f = (const uint4*)(ws + WS_WP1);
  const float* misc = (const float*)(ws + WS_MISC);

  const int e0 = off[base];
  const int e1 = off[base + NB];

  // prologue prefetch of tile 0's edge metadata (overlaps zero-init+barrier)
  int pr = 0, pc = 0;
  float prx = 0.f, pry = 0.f, prz = 0.f, pcx = 0.f, pcy = 0.f, pcz = 0.f;
  if (tid < ET) {
    int e = e0 + tid;
    e = e < EDGES ? e : EDGES - 1;
    const u32x2 rc = *(const u32x2*)(srec + 2 * (size_t)e);
    pr = (int)rc[0];
    pc = (int)rc[1];
    prx = pos[3 * pr + 0]; pry = pos[3 * pr + 1]; prz = pos[3 * pr + 2];
    pcx = pos[3 * pc + 0]; pcy = pos[3 * pc + 1]; pcz = pos[3 * pc + 2];
  }

  for (int i = tid; i < NB * 68; i += 256) sAccX[i] = 0.f;
  __syncthreads();

  const int et0 = wave * 2;
  const floatx4 fzero = {0.f, 0.f, 0.f, 0.f};

#pragma unroll 1
  for (int t0 = e0; t0 < e1; t0 += ET) {
    // ---- phase A: write prefetched edge metadata to LDS (no global loads)
    if (tid < ET) {
      const float r0 = prx - pcx;
      const float r1 = pry - pcy;
      const float r2 = prz - pcz;
      int lc = pc - base;
      lc = (lc < 0) ? 0 : ((lc > NB - 1) ? NB - 1 : lc);
      sRowE[tid] = pr;
      sLC[tid] = lc;
      sRel[3 * tid + 0] = r0;
      sRel[3 * tid + 1] = r1;
      sRel[3 * tid + 2] = r2;
      sDist[tid] = r0 * r0 + r1 * r1 + r2 * r2;
    }
    __syncthreads();

    // ---- phase B: coalesced gathers, 16 lanes per node row.
    // half 0: x[row] -> kt 0..1 ; half 1: x[col] -> kt 2..3 (sorted, L1-hot)
    // inner loop fully unrolled: 8 loads in flight (was 16 serial latencies)
#pragma unroll 1
    for (int half = 0; half < 2; ++half) {
      float4 v[8];
#pragma unroll
      for (int i = 0; i < 8; ++i) {
        const int s = wave * 32 + i * 4 + (lane >> 4);  // edge slot in tile
        const int node = half ? (base + sLC[s]) : sRowE[s];
        v[i] = *(const float4*)(x + (size_t)node * 64 + (lane & 15) * 4);
      }
#pragma unroll
      for (int i = 0; i < 8; ++i) {
        const int s = wave * 32 + i * 4 + (lane >> 4);
        const int kq = lane & 15;
        const int et = s >> 4;
        const int kt = (half << 1) | (kq >> 3);
        const int fl = (((kq >> 1) & 3) << 4) | (s & 15);
        u32x2 d;
        d[0] = pack2bf(v[i].x, v[i].y);
        d[1] = pack2bf(v[i].z, v[i].w);
        *((u32x2*)&sFeat[(et * 4 + kt) * 64 + fl] + (kq & 1)) = d;
      }
    }
    // no barrier: sFeat is wave-private; sLC/sRel/sDist covered by A-barrier

    // ---- prefetch next tile's srec (latency hides under phi_pos)
    u32x2 rcN;
    rcN[0] = 0; rcN[1] = 0;
    if (tid < ET) {
      int e = t0 + ET + tid;
      e = e < EDGES ? e : EDGES - 1;
      rcN = *(const u32x2*)(srec + 2 * (size_t)e);
    }

    // ---- phi_pos (mm-paired, kt unroll 1) + segmented-scan scatter
    {
      floatx4 accp[2][8];
#pragma unroll
      for (int m = 0; m < 2; ++m)
#pragma unroll
        for (int j = 0; j < 8; ++j) accp[m][j] = fzero;
#pragma unroll 1
      for (int kt = 0; kt < 2; ++kt) {  // x_row occupies k 0..63
        const short8 b0 = __builtin_bit_cast(short8, sFeat[((et0 + 0) * 4 + kt) * 64 + lane]);
        const short8 b1 = __builtin_bit_cast(short8, sFeat[((et0 + 1) * 4 + kt) * 64 + lane]);
#pragma unroll
        for (int jt = 0; jt < 8; ++jt) {
          const short8 a = __builtin_bit_cast(short8, wp1f[(kt * 8 + jt) * 64 + lane]);
          accp[0][jt] = MFMA(a, b0, accp[0][jt]);
          accp[1][jt] = MFMA(a, b1, accp[1][jt]);
        }
      }
#pragma unroll
      for (int m = 0; m < 2; ++m) {
        float s = 0.f;
#pragma unroll
        for (int jt = 0; jt < 8; ++jt) {
          const float4 bp = *(const float4*)(misc + 192 + jt * 16 + q * 4);
          const float4 wp = *(const float4*)(misc + 320 + jt * 16 + q * 4);
          s += fast_silu(accp[m][jt][0] + bp.x) * wp.x;
          s += fast_silu(accp[m][jt][1] + bp.y) * wp.y;
          s += fast_silu(accp[m][jt][2] + bp.z) * wp.z;
          s += fast_silu(accp[m][jt][3] + bp.w) * wp.w;
        }
        s += __shfl_xor(s, 16);
        s += __shfl_xor(s, 32);
        const float wv = s + misc[448];  // all 64 lanes hold per-nn value

        const int el = (et0 + m) * 16 + nn;
        const bool vE = (t0 + el) < e1;
        int lcv = sLC[el];
        if (!vE) lcv = -1 - nn;  // singleton segments for invalid lanes
        // unconditional DPPs (convergent!) then bitwise combines:
        const int k1 = dpp_i<0x111>(lcv);
        const int k2 = dpp_i<0x112>(lcv);
        const int k4 = dpp_i<0x114>(lcv);
        const int k8 = dpp_i<0x118>(lcv);
        const int kn = dpp_i<0x101>(lcv);
        const bool m1 = (nn >= 1) & (k1 == lcv);
        const bool m2 = (nn >= 2) & (k2 == lcv);
        const bool m4 = (nn >= 4) & (k4 == lcv);
        const bool m8 = (nn >= 8) & (k8 == lcv);
        const bool tail = vE & ((nn == 15) | (kn != lcv));

        float p0 = segscan(wv * sRel[3 * el + 0], m1, m2, m4, m8);
        float p1 = segscan(wv * sRel[3 * el + 1], m1, m2, m4, m8);
        float p2 = segscan(wv * sRel[3 * el + 2], m1, m2, m4, m8);
        if (tail && q == 0) {
          float* ap = sAccX + lcv * 68 + 64;  // pos acc lives in the pad
          lds_add(ap + 0, p0);
          lds_add(ap + 1, p1);
          lds_add(ap + 2, p2);
        }
      }
    }

    // ---- prefetch next tile's pos (srec arrived during phi_pos; these
    // loads fly during GEMM1+GEMM2; ~8 VGPR live — metadata only)
    if (tid < ET) {
      pr = (int)rcN[0];
      pc = (int)rcN[1];
      prx = pos[3 * pr + 0]; pry = pos[3 * pr + 1]; prz = pos[3 * pr + 2];
      pcx = pos[3 * pc + 0]; pcy = pos[3 * pc + 1]; pcz = pos[3 * pc + 2];
    }

    // ---- GEMM1 (mm-paired) + epilogue 1
    {
      floatx4 acc1[2][8];
#pragma unroll
      for (int m = 0; m < 2; ++m)
#pragma unroll
        for (int j = 0; j < 8; ++j) acc1[m][j] = fzero;
#pragma unroll 1
      for (int kt = 0; kt < 4; ++kt) {
        const short8 b0 = __builtin_bit_cast(short8, sFeat[((et0 + 0) * 4 + kt) * 64 + lane]);
        const short8 b1 = __builtin_bit_cast(short8, sFeat[((et0 + 1) * 4 + kt) * 64 + lane]);
#pragma unroll
        for (int jt = 0; jt < 8; ++jt) {
          const short8 a = __builtin_bit_cast(short8, wx1f[(kt * 8 + jt) * 64 + lane]);
          acc1[0][jt] = MFMA(a, b0, acc1[0][jt]);
          acc1[1][jt] = MFMA(a, b1, acc1[1][jt]);
        }
      }
#pragma unroll
      for (int m = 0; m < 2; ++m) {
        const int etG = et0 + m;
        const float dist = sDist[etG * 16 + nn];
#pragma unroll
        for (int jt = 0; jt < 8; ++jt) {
          const float4 bx = *(const float4*)(misc + 0 + jt * 16 + q * 4);
          const float4 wd = *(const float4*)(misc + 456 + jt * 16 + q * 4);
          const unsigned int h01 = pack2bf(fast_silu(acc1[m][jt][0] + bx.x + dist * wd.x),
                                           fast_silu(acc1[m][jt][1] + bx.y + dist * wd.y));
          const unsigned int h23 = pack2bf(fast_silu(acc1[m][jt][2] + bx.z + dist * wd.z),
                                           fast_silu(acc1[m][jt][3] + bx.w + dist * wd.w));
          const int j0 = jt * 16 + q * 4;
          const int kt2 = j0 >> 5;
          const int lane2 = (((j0 & 31) >> 3) << 4) | nn;
          const int byteoff = (j0 & 7) << 1;
          uint2* dst = (uint2*)((char*)sFeat +
                                (((size_t)((etG * 4 + kt2) * 64 + lane2)) << 4) + byteoff);
          *dst = make_uint2(h01, h23);
        }
      }
    }

    // ---- GEMM2 (mm-paired) + segmented-scan scatter epilogue
    {
      floatx4 acc2[2][4];
#pragma unroll
      for (int m = 0; m < 2; ++m)
#pragma unroll
        for (int it = 0; it < 4; ++it) acc2[m][it] = fzero;
#pragma unroll 1
      for (int kt = 0; kt < 4; ++kt) {
        const short8 b0 = __builtin_bit_cast(short8, sFeat[((et0 + 0) * 4 + kt) * 64 + lane]);
        const short8 b1 = __builtin_bit_cast(short8, sFeat[((et0 + 1) * 4 + kt) * 64 + lane]);
#pragma unroll
        for (int it = 0; it < 4; ++it) {
          const short8 a = __builtin_bit_cast(short8, wx2f[(kt * 4 + it) * 64 + lane]);
          acc2[0][it] = MFMA(a, b0, acc2[0][it]);
          acc2[1][it] = MFMA(a, b1, acc2[1][it]);
        }
      }
#pragma unroll
      for (int m = 0; m < 2; ++m) {
        const int el = (et0 + m) * 16 + nn;
        const bool vE = (t0 + el) < e1;
        int lcv = sLC[el];
        if (!vE) lcv = -1 - nn;
        const int k1 = dpp_i<0x111>(lcv);
        const int k2 = dpp_i<0x112>(lcv);
        const int k4 = dpp_i<0x114>(lcv);
        const int k8 = dpp_i<0x118>(lcv);
        const int kn = dpp_i<0x101>(lcv);
        const bool m1 = (nn >= 1) & (k1 == lcv);
        const bool m2 = (nn >= 2) & (k2 == lcv);
        const bool m4 = (nn >= 4) & (k4 == lcv);
        const bool m8 = (nn >= 8) & (k8 == lcv);
        const bool tail = vE & ((nn == 15) | (kn != lcv));
#pragma unroll
        for (int it = 0; it < 4; ++it) {
          const float4 b2 = *(const float4*)(misc + 128 + it * 16 + q * 4);
          float v0 = segscan(acc2[m][it][0] + b2.x, m1, m2, m4, m8);
          float v1 = segscan(acc2[m][it][1] + b2.y, m1, m2, m4, m8);
          float v2 = segscan(acc2[m][it][2] + b2.z, m1, m2, m4, m8);
          float v3 = segscan(acc2[m][it][3] + b2.w, m1, m2, m4, m8);
          if (tail) {
            float* arow = sAccX + lcv * 68;
            const int i0 = it * 16 + q * 4;
            lds_add(arow + i0 + 0, v0);
            lds_add(arow + i0 + 1, v1);
            lds_add(arow + i0 + 2, v2);
            lds_add(arow + i0 + 3, v3);
          }
        }
      }
    }
    __syncthreads();
  }

  // ---- final coalesced stores (no global atomics)
  {
    const int n = base + (tid >> 2);
    if (n < NODES) {
      const int c0 = (tid & 3) * 16;
      float* orow = out + (size_t)n * 64 + c0;
      const float* arow = sAccX + (tid >> 2) * 68 + c0;
#pragma unroll
      for (int j = 0; j < 16; j += 4) *(float4*)(orow + j) = *(const float4*)(arow + j);
    }
    if (tid < 192) {
      const int idx = base * 3 + tid;
      if (idx < NODES * 3)
        out[(size_t)NODES * 64 + idx] = sAccX[(tid / 3) * 68 + 64 + (tid % 3)];
    }
  }
}

extern "C" void kernel_launch(void* const* d_in, const int* in_sizes, int n_in,
                              void* d_out, int out_size, void* d_ws, size_t ws_size,
                              hipStream_t stream) {
  (void)in_sizes; (void)n_in; (void)ws_size; (void)out_size;
  const float* x = (const float*)d_in[0];
  const float* pos = (const float*)d_in[1];
  const int* ei = (const int*)d_in[2];
  const float* Wx1 = (const float*)d_in[3];
  const float* bx1 = (const float*)d_in[4];
  const float* Wx2 = (const float*)d_in[5];
  const float* bx2 = (const float*)d_in[6];
  const float* Wp1 = (const float*)d_in[7];
  const float* bp1 = (const float*)d_in[8];
  const float* Wp2 = (const float*)d_in[9];
  const float* bp2 = (const float*)d_in[10];
  float* out = (float*)d_out;
  unsigned char* ws = (unsigned char*)d_ws;

  int* counts = (int*)(ws + WS_CNT);   // aliased with cursor (scan3 rewrites)
  int* cursor = (int*)(ws + WS_CNT);
  int* off = (int*)(ws + WS_OFF);
  int* tmp = (int*)(ws + WS_TMP);      // aliased with srec (dies before scatter)
  int* bsum = (int*)(ws + WS_BSUM);
  int* bsumx = (int*)(ws + WS_BSUMX);
  unsigned int* srec = (unsigned int*)(ws + WS_SREC);

  hipMemsetAsync(counts, 0, (size_t)NODES * sizeof(int), stream);
  prep_kernel<<<16, 256, 0, stream>>>(Wx1, Wx2, Wp1, bx1, bx2, bp1, Wp2, bp2, ws);
  const int eb = (EDGES + 255) / 256;
  hist_kernel<<<eb, 256, 0, stream>>>(ei, counts);
  scan1_kernel<<<SCB, 1024, 0, stream>>>(counts, tmp, bsum);
  scan2_kernel<<<1, 128, 0, stream>>>(bsum, bsumx);
  scan3_kernel<<<SCB, 1024, 0, stream>>>(counts, tmp, bsumx, off, cursor);
  scatter_kernel<<<eb, 256, 0, stream>>>(ei, cursor, srec);
  node_kernel<<<NBLK, 256, 0, stream>>>(x, pos, ws, out);
}

// Round 3
// 467.721 us; speedup vs baseline: 3.0393x; 1.7122x over previous
//
#include <hip/hip_runtime.h>

#define EDGES 1000000
#define NODES 100000
#define ET 128   // edges per tile
#define NB 64    // nodes per block (node_kernel)
#define NBLK ((NODES + NB - 1) / NB)  // 1563
#define NBW ((NODES + 127) / 128)     // 782 wpos blocks

typedef short short8 __attribute__((ext_vector_type(8)));
typedef float floatx4 __attribute__((ext_vector_type(4)));
typedef unsigned int u32x2 __attribute__((ext_vector_type(2)));
typedef unsigned int u32x4 __attribute__((ext_vector_type(4)));

#define MFMA(a, b, c) __builtin_amdgcn_mfma_f32_16x16x32_bf16(a, b, c, 0, 0, 0)

// ws layout (bytes)
#define WS_WX1 0        // 32768: Wx1 bf16 frags
#define WS_WX2 32768    // 16384: Wx2 frags
#define WS_WP1 49152    // 16384: Wp1 frags
#define WS_MISC 65536   // 2048: biases etc (floats)
#define WS_OFF 68608    // off[100128] int = 400512 B (CSR offsets, padded)
#define WS_CNT 469504   // counts/cursor[100000] int = 400000 B (aliased)
#define WS_SREC 917504  // uint2[EDGES] = 8 MB sorted (row,col) records
#define WS_POSW 8917504 // float4[NODES] = 1.6 MB {pos.xyz, w_pos} per node
// scan temporaries alias the srec region (they die before scatter writes srec):
#define WS_TMP WS_SREC                 // int[100352] inclusive per-block scans
#define WS_BSUM (WS_SREC + 401408)     // int[98] block sums
#define WS_BSUMX (WS_SREC + 402432)    // int[128] exclusive-scanned block sums

__device__ __forceinline__ unsigned short f2bf(float f) {
  union { float f; unsigned int u; } c;
  c.f = f;
  unsigned int u = c.u;
  u += 0x7fffu + ((u >> 16) & 1u);
  return (unsigned short)(u >> 16);
}

__device__ __forceinline__ unsigned int pack2bf(float lo, float hi) {
  return (unsigned int)f2bf(lo) | ((unsigned int)f2bf(hi) << 16);
}

// single-instruction RNE pack (same rounding as f2bf); no builtin on gfx950
__device__ __forceinline__ unsigned int cvtpk2bf(float lo, float hi) {
  unsigned int r;
  asm("v_cvt_pk_bf16_f32 %0, %1, %2" : "=v"(r) : "v"(lo), "v"(hi));
  return r;
}

__device__ __forceinline__ float fast_silu(float v) {
#if __has_builtin(__builtin_amdgcn_exp2f) && __has_builtin(__builtin_amdgcn_rcpf)
  float e = __builtin_amdgcn_exp2f(-1.44269504088896340736f * v);
  return v * __builtin_amdgcn_rcpf(1.0f + e);
#else
  return v / (1.0f + __expf(-v));
#endif
}

// DPP cross-lane within 16-lane rows. row_shr:N = lane i reads lane i-N.
// MUST be called unconditionally in straight-line code (convergent ops).
template <int CTRL>
__device__ __forceinline__ int dpp_i(int v) {
  return __builtin_amdgcn_update_dpp(0, v, CTRL, 0xf, 0xf, true);
}
template <int CTRL>
__device__ __forceinline__ float dpp_f(float v) {
  return __builtin_bit_cast(float, dpp_i<CTRL>(__builtin_bit_cast(int, v)));
}

// Segmented inclusive prefix-sum across nn (16-lane row), segments = runs of
// equal sorted keys; masks m1..m8 from unconditional key equality at d=1,2,4,8.
__device__ __forceinline__ float segscan(float v, bool m1, bool m2, bool m4, bool m8) {
  float t;
  t = dpp_f<0x111>(v); v += m1 ? t : 0.f;
  t = dpp_f<0x112>(v); v += m2 ? t : 0.f;
  t = dpp_f<0x114>(v); v += m4 ? t : 0.f;
  t = dpp_f<0x118>(v); v += m8 ? t : 0.f;
  return v;
}

__device__ __forceinline__ void lds_add(float* p, float v) {
  __hip_atomic_fetch_add(p, v, __ATOMIC_RELAXED, __HIP_MEMORY_SCOPE_WORKGROUP);
}

__global__ __launch_bounds__(256) void prep_kernel(
    const float* __restrict__ Wx1, const float* __restrict__ Wx2,
    const float* __restrict__ Wp1, const float* __restrict__ bx1,
    const float* __restrict__ bx2, const float* __restrict__ bp1,
    const float* __restrict__ Wp2, const float* __restrict__ bp2,
    unsigned char* __restrict__ ws) {
  const int t = blockIdx.x * 256 + threadIdx.x;
  const int nthr = gridDim.x * 256;

  for (int task = t; task < 2048; task += nthr) {  // Wx1[0:128][0:128]
    const int n = task & 127;
    const int kb = task >> 7;
    const int k0 = kb << 3;
    unsigned int d[4];
#pragma unroll
    for (int i = 0; i < 4; ++i)
      d[i] = pack2bf(Wx1[(k0 + 2 * i) * 128 + n], Wx1[(k0 + 2 * i + 1) * 128 + n]);
    const int lane = ((kb & 3) << 4) | (n & 15);
    const int frag = ((kb >> 2) << 3) | (n >> 4);
    *(uint4*)(ws + WS_WX1 + ((size_t)(frag * 64 + lane) << 4)) =
        make_uint4(d[0], d[1], d[2], d[3]);
  }
  for (int task = t; task < 1024; task += nthr) {  // Wx2[0:128][0:64]
    const int n = task & 63;
    const int kb = task >> 6;
    const int k0 = kb << 3;
    unsigned int d[4];
#pragma unroll
    for (int i = 0; i < 4; ++i)
      d[i] = pack2bf(Wx2[(k0 + 2 * i) * 64 + n], Wx2[(k0 + 2 * i + 1) * 64 + n]);
    const int lane = ((kb & 3) << 4) | (n & 15);
    const int frag = ((kb >> 2) << 2) | (n >> 4);
    *(uint4*)(ws + WS_WX2 + ((size_t)(frag * 64 + lane) << 4)) =
        make_uint4(d[0], d[1], d[2], d[3]);
  }
  for (int task = t; task < 1024; task += nthr) {  // Wp1[0:64][0:128]
    const int n = task & 127;
    const int kb = task >> 7;
    const int k0 = kb << 3;
    unsigned int d[4];
#pragma unroll
    for (int i = 0; i < 4; ++i)
      d[i] = pack2bf(Wp1[(k0 + 2 * i) * 128 + n], Wp1[(k0 + 2 * i + 1) * 128 + n]);
    const int lane = ((kb & 3) << 4) | (n & 15);
    const int frag = ((kb >> 2) << 3) | (n >> 4);
    *(uint4*)(ws + WS_WP1 + ((size_t)(frag * 64 + lane) << 4)) =
        make_uint4(d[0], d[1], d[2], d[3]);
  }
  float* misc = (float*)(ws + WS_MISC);
  for (int i = t; i < 128; i += nthr) misc[i] = bx1[i];
  for (int i = t; i < 64; i += nthr) misc[128 + i] = bx2[i];
  for (int i = t; i < 128; i += nthr) misc[192 + i] = bp1[i];
  for (int i = t; i < 128; i += nthr) misc[320 + i] = Wp2[i];
  if (t == 0) misc[448] = bp2[0];
  for (int i = t; i < 128; i += nthr) misc[456 + i] = Wx1[128 * 128 + i];
}

// ---- R12: per-NODE phi_pos precompute ----
// weight_pos = phi_pos(x[row]) depends only on the row node, but the old
// node_kernel evaluated it per-EDGE (1M times vs 100K needed). Precompute
// w[n] once per node here and emit posw[n] = {pos.xyz, w} as one aligned
// float4 so node_kernel's scattered pos reads collapse from 6 dwords to 2
// float4s per edge. Numerically identical pipeline: same bf16 pack, same
// MFMA order, same epilogue.
__global__ __launch_bounds__(256) void wpos_kernel(
    const float* __restrict__ x, const float* __restrict__ pos,
    unsigned char* __restrict__ ws) {
  const uint4* wp1f = (const uint4*)(ws + WS_WP1);
  const float* misc = (const float*)(ws + WS_MISC);
  float* posw = (float*)(ws + WS_POSW);

  const int tid = threadIdx.x;
  const int lane = tid & 63;
  const int wave = tid >> 6;
  const int q = lane >> 4;
  const int nn = lane & 15;
  const int base = blockIdx.x * 128 + wave * 32;  // this wave: nodes base..base+31

  // B-operand frags straight from global: lane l of frag kt holds
  // x[node(l&15)][kt*32 + (l>>4)*8 .. +7] (same layout the LDS staging built)
  short8 bf[2][2];
#pragma unroll
  for (int m = 0; m < 2; ++m) {
    int node = base + m * 16 + nn;
    node = node < NODES ? node : NODES - 1;
#pragma unroll
    for (int kt = 0; kt < 2; ++kt) {
      const int k0 = kt * 32 + q * 8;
      const float4 a = *(const float4*)(x + (size_t)node * 64 + k0);
      const float4 b = *(const float4*)(x + (size_t)node * 64 + k0 + 4);
      u32x4 d;
      d[0] = cvtpk2bf(a.x, a.y);
      d[1] = cvtpk2bf(a.z, a.w);
      d[2] = cvtpk2bf(b.x, b.y);
      d[3] = cvtpk2bf(b.z, b.w);
      bf[m][kt] = __builtin_bit_cast(short8, d);
    }
  }

  const floatx4 fzero = {0.f, 0.f, 0.f, 0.f};
  floatx4 accp[2][8];
#pragma unroll
  for (int m = 0; m < 2; ++m)
#pragma unroll
    for (int j = 0; j < 8; ++j) accp[m][j] = fzero;
#pragma unroll 1
  for (int kt = 0; kt < 2; ++kt) {
#pragma unroll
    for (int jt = 0; jt < 8; ++jt) {
      const short8 a = __builtin_bit_cast(short8, wp1f[(kt * 8 + jt) * 64 + lane]);
      accp[0][jt] = MFMA(a, bf[0][kt], accp[0][jt]);
      accp[1][jt] = MFMA(a, bf[1][kt], accp[1][jt]);
    }
  }
#pragma unroll
  for (int m = 0; m < 2; ++m) {
    float s = 0.f;
#pragma unroll
    for (int jt = 0; jt < 8; ++jt) {
      const float4 bp = *(const float4*)(misc + 192 + jt * 16 + q * 4);
      const float4 wp = *(const float4*)(misc + 320 + jt * 16 + q * 4);
      s += fast_silu(accp[m][jt][0] + bp.x) * wp.x;
      s += fast_silu(accp[m][jt][1] + bp.y) * wp.y;
      s += fast_silu(accp[m][jt][2] + bp.z) * wp.z;
      s += fast_silu(accp[m][jt][3] + bp.w) * wp.w;
    }
    s += __shfl_xor(s, 16);
    s += __shfl_xor(s, 32);
    const int node = base + m * 16 + nn;
    if (q == 0 && node < NODES) {
      float4 o;
      o.x = pos[3 * node + 0];
      o.y = pos[3 * node + 1];
      o.z = pos[3 * node + 2];
      o.w = s + misc[448];
      *(float4*)(posw + 4 * (size_t)node) = o;
    }
  }
}

// ---- counting sort by col ----
__global__ __launch_bounds__(256) void hist_kernel(const int* __restrict__ ei,
                                                   int* __restrict__ counts) {
  const int t = blockIdx.x * 256 + threadIdx.x;
  if (t < EDGES) {
    int c = __builtin_nontemporal_load(ei + EDGES + t);
    c = (c < 0) ? 0 : ((c >= NODES) ? NODES - 1 : c);
    atomicAdd(&counts[c], 1);
  }
}

#define SCB 98  // blocks of 1024: 98*1024 = 100352 >= NODES+128

__global__ __launch_bounds__(1024) void scan1_kernel(const int* __restrict__ counts,
                                                     int* __restrict__ tmp,
                                                     int* __restrict__ bsum) {
  __shared__ int part[1024];
  const int t = threadIdx.x;
  const int i = blockIdx.x * 1024 + t;
  int v = (i < NODES) ? counts[i] : 0;
  part[t] = v;
  __syncthreads();
  for (int d = 1; d < 1024; d <<= 1) {
    int u = 0;
    if (t >= d) u = part[t - d];
    __syncthreads();
    if (t >= d) part[t] += u;
    __syncthreads();
  }
  tmp[i] = part[t];  // inclusive scan within block
  if (t == 1023) bsum[blockIdx.x] = part[1023];
}

__global__ __launch_bounds__(128) void scan2_kernel(const int* __restrict__ bsum,
                                                    int* __restrict__ bsumx) {
  __shared__ int part[128];
  const int t = threadIdx.x;
  int v = (t < SCB) ? bsum[t] : 0;
  part[t] = v;
  __syncthreads();
  for (int d = 1; d < 128; d <<= 1) {
    int u = 0;
    if (t >= d) u = part[t - d];
    __syncthreads();
    if (t >= d) part[t] += u;
    __syncthreads();
  }
  bsumx[t] = part[t] - v;  // exclusive
}

__global__ __launch_bounds__(1024) void scan3_kernel(const int* __restrict__ counts,
                                                     const int* __restrict__ tmp,
                                                     const int* __restrict__ bsumx,
                                                     int* __restrict__ off,
                                                     int* __restrict__ cursor) {
  const int i = blockIdx.x * 1024 + threadIdx.x;
  if (i < NODES) {
    const int cn = counts[i];  // read before cursor write (aliased with counts)
    const int o = bsumx[blockIdx.x] + tmp[i] - cn;
    off[i] = o;
    cursor[i] = o;
  } else if (i < NODES + 128) {
    off[i] = EDGES;
  }
}

__global__ __launch_bounds__(256) void scatter_kernel(const int* __restrict__ ei,
                                                      int* __restrict__ cursor,
                                                      unsigned int* __restrict__ srec) {
  const int t = blockIdx.x * 256 + threadIdx.x;
  if (t < EDGES) {
    int r = __builtin_nontemporal_load(ei + t);
    int c = __builtin_nontemporal_load(ei + EDGES + t);
    r = (r < 0) ? 0 : ((r >= NODES) ? NODES - 1 : r);
    c = (c < 0) ? 0 : ((c >= NODES) ? NODES - 1 : c);
    const int p = atomicAdd(&cursor[c], 1);
    srec[2 * (size_t)p] = (unsigned)r;
    srec[2 * (size_t)p + 1] = (unsigned)c;
  }
}

// ---- main: node-centric, zero global atomics ----
// R12 on the R11 skeleton:
// (a) phi_pos GEMM+epilogue removed (precomputed per node by wpos_kernel);
//     the pos segscan-scatter merged into GEMM2's epilogue (reuses masks);
// (b) edge pos reads = 2 aligned float4s from posw (was 6 scattered dwords);
// (c) phase B: single 16-load batch (both halves in flight; no accs live
//     there, peak ~110 VGPR < 170 cap — unlike R10's 220+ which spilled);
// (d) v_cvt_pk_bf16_f32 replaces the 5-op manual pack at hot sites;
// (e) srec prefetch issued before phase B (covers under B), posw prefetch
//     after B (covers under GEMM1+GEMM2).
// kt loops stay unroll(1) (anti-spill, r3-r5 lesson).
__global__ __launch_bounds__(256, 3) void node_kernel(
    const float* __restrict__ x, const unsigned char* __restrict__ ws,
    float* __restrict__ out) {
  __shared__ uint4 sFeat[2048];                    // 32 KB B-operand frags
  __shared__ __align__(16) float sAccX[NB * 68];   // 17 KB; cols 64..66 = pos acc
  __shared__ float sRel[ET * 3];
  __shared__ float sDist[ET];
  __shared__ float sW[ET];
  __shared__ int sLC[ET];
  __shared__ int sRowE[ET];

  const int tid = threadIdx.x;
  const int lane = tid & 63;
  const int wave = tid >> 6;
  const int q = lane >> 4;
  const int nn = lane & 15;
  const int base = blockIdx.x * NB;

  const int* off = (const int*)(ws + WS_OFF);
  const unsigned int* srec = (const unsigned int*)(ws + WS_SREC);
  const uint4* wx1f = (const uint4*)(ws + WS_WX1);
  const uint4* wx2f = (const uint4*)(ws + WS_WX2);
  const float* misc = (const float*)(ws + WS_MISC);
  const float* posw = (const float*)(ws + WS_POSW);

  const int e0 = off[base];
  const int e1 = off[base + NB];

  // prologue prefetch of tile 0's edge metadata (overlaps zero-init+barrier)
  int pr = 0, pc = 0;
  float4 pR = {0.f, 0.f, 0.f, 0.f}, pC = {0.f, 0.f, 0.f, 0.f};
  if (tid < ET) {
    int e = e0 + tid;
    e = e < EDGES ? e : EDGES - 1;
    const u32x2 rc = *(const u32x2*)(srec + 2 * (size_t)e);
    pr = (int)rc[0];
    pc = (int)rc[1];
    pR = *(const float4*)(posw + 4 * (size_t)pr);
    pC = *(const float4*)(posw + 4 * (size_t)pc);
  }

  for (int i = tid; i < NB * 68; i += 256) sAccX[i] = 0.f;
  __syncthreads();

  const int et0 = wave * 2;
  const floatx4 fzero = {0.f, 0.f, 0.f, 0.f};

#pragma unroll 1
  for (int t0 = e0; t0 < e1; t0 += ET) {
    // ---- phase A: write prefetched edge metadata to LDS (no global loads)
    if (tid < ET) {
      const float r0 = pR.x - pC.x;
      const float r1 = pR.y - pC.y;
      const float r2 = pR.z - pC.z;
      int lc = pc - base;
      lc = (lc < 0) ? 0 : ((lc > NB - 1) ? NB - 1 : lc);
      sRowE[tid] = pr;
      sLC[tid] = lc;
      sW[tid] = pR.w;
      sRel[3 * tid + 0] = r0;
      sRel[3 * tid + 1] = r1;
      sRel[3 * tid + 2] = r2;
      sDist[tid] = r0 * r0 + r1 * r1 + r2 * r2;
    }
    __syncthreads();

    // ---- prefetch next tile's srec (arrives during phase B)
    u32x2 rcN;
    rcN[0] = 0; rcN[1] = 0;
    if (tid < ET) {
      int e = t0 + ET + tid;
      e = e < EDGES ? e : EDGES - 1;
      rcN = *(const u32x2*)(srec + 2 * (size_t)e);
    }

    // ---- phase B: coalesced gathers, 16 lanes per node row; all 16 loads
    // of both halves batched in flight (no accumulators live here).
    {
      int nodeid[16];
#pragma unroll
      for (int i = 0; i < 8; ++i) {
        const int s = wave * 32 + i * 4 + (lane >> 4);
        nodeid[i] = sRowE[s];           // half 0: x[row]
        nodeid[8 + i] = base + sLC[s];  // half 1: x[col] (sorted, L1-hot)
      }
      float4 v[16];
#pragma unroll
      for (int i = 0; i < 16; ++i)
        v[i] = *(const float4*)(x + (size_t)nodeid[i] * 64 + (lane & 15) * 4);
#pragma unroll
      for (int i = 0; i < 16; ++i) {
        const int half = i >> 3;
        const int s = wave * 32 + (i & 7) * 4 + (lane >> 4);
        const int kq = lane & 15;
        const int et = s >> 4;
        const int kt = (half << 1) | (kq >> 3);
        const int fl = (((kq >> 1) & 3) << 4) | (s & 15);
        u32x2 d;
        d[0] = cvtpk2bf(v[i].x, v[i].y);
        d[1] = cvtpk2bf(v[i].z, v[i].w);
        *((u32x2*)&sFeat[(et * 4 + kt) * 64 + fl] + (kq & 1)) = d;
      }
    }
    // no barrier: sFeat is wave-private; sLC/sRel/sDist/sW covered by A-barrier

    // ---- prefetch next tile's posw (rcN arrived during B; these float4
    // loads fly during GEMM1+GEMM2; ~10 VGPR live — metadata only)
    if (tid < ET) {
      pr = (int)rcN[0];
      pc = (int)rcN[1];
      pR = *(const float4*)(posw + 4 * (size_t)pr);
      pC = *(const float4*)(posw + 4 * (size_t)pc);
    }

    // ---- GEMM1 (mm-paired) + epilogue 1
    {
      floatx4 acc1[2][8];
#pragma unroll
      for (int m = 0; m < 2; ++m)
#pragma unroll
        for (int j = 0; j < 8; ++j) acc1[m][j] = fzero;
#pragma unroll 1
      for (int kt = 0; kt < 4; ++kt) {
        const short8 b0 = __builtin_bit_cast(short8, sFeat[((et0 + 0) * 4 + kt) * 64 + lane]);
        const short8 b1 = __builtin_bit_cast(short8, sFeat[((et0 + 1) * 4 + kt) * 64 + lane]);
#pragma unroll
        for (int jt = 0; jt < 8; ++jt) {
          const short8 a = __builtin_bit_cast(short8, wx1f[(kt * 8 + jt) * 64 + lane]);
          acc1[0][jt] = MFMA(a, b0, acc1[0][jt]);
          acc1[1][jt] = MFMA(a, b1, acc1[1][jt]);
        }
      }
#pragma unroll
      for (int m = 0; m < 2; ++m) {
        const int etG = et0 + m;
        const float dist = sDist[etG * 16 + nn];
#pragma unroll
        for (int jt = 0; jt < 8; ++jt) {
          const float4 bx = *(const float4*)(misc + 0 + jt * 16 + q * 4);
          const float4 wd = *(const float4*)(misc + 456 + jt * 16 + q * 4);
          const unsigned int h01 = cvtpk2bf(fast_silu(acc1[m][jt][0] + bx.x + dist * wd.x),
                                            fast_silu(acc1[m][jt][1] + bx.y + dist * wd.y));
          const unsigned int h23 = cvtpk2bf(fast_silu(acc1[m][jt][2] + bx.z + dist * wd.z),
                                            fast_silu(acc1[m][jt][3] + bx.w + dist * wd.w));
          const int j0 = jt * 16 + q * 4;
          const int kt2 = j0 >> 5;
          const int lane2 = (((j0 & 31) >> 3) << 4) | nn;
          const int byteoff = (j0 & 7) << 1;
          uint2* dst = (uint2*)((char*)sFeat +
                                (((size_t)((etG * 4 + kt2) * 64 + lane2)) << 4) + byteoff);
          *dst = make_uint2(h01, h23);
        }
      }
    }

    // ---- GEMM2 (mm-paired) + merged segmented-scan scatter epilogue
    // (x-features AND pos update share one mask computation per m)
    {
      floatx4 acc2[2][4];
#pragma unroll
      for (int m = 0; m < 2; ++m)
#pragma unroll
        for (int it = 0; it < 4; ++it) acc2[m][it] = fzero;
#pragma unroll 1
      for (int kt = 0; kt < 4; ++kt) {
        const short8 b0 = __builtin_bit_cast(short8, sFeat[((et0 + 0) * 4 + kt) * 64 + lane]);
        const short8 b1 = __builtin_bit_cast(short8, sFeat[((et0 + 1) * 4 + kt) * 64 + lane]);
#pragma unroll
        for (int it = 0; it < 4; ++it) {
          const short8 a = __builtin_bit_cast(short8, wx2f[(kt * 4 + it) * 64 + lane]);
          acc2[0][it] = MFMA(a, b0, acc2[0][it]);
          acc2[1][it] = MFMA(a, b1, acc2[1][it]);
        }
      }
#pragma unroll
      for (int m = 0; m < 2; ++m) {
        const int el = (et0 + m) * 16 + nn;
        const bool vE = (t0 + el) < e1;
        int lcv = sLC[el];
        if (!vE) lcv = -1 - nn;  // singleton segments for invalid lanes
        // unconditional DPPs (convergent!) then bitwise combines:
        const int k1 = dpp_i<0x111>(lcv);
        const int k2 = dpp_i<0x112>(lcv);
        const int k4 = dpp_i<0x114>(lcv);
        const int k8 = dpp_i<0x118>(lcv);
        const int kn = dpp_i<0x101>(lcv);
        const bool m1 = (nn >= 1) & (k1 == lcv);
        const bool m2 = (nn >= 2) & (k2 == lcv);
        const bool m4 = (nn >= 4) & (k4 == lcv);
        const bool m8 = (nn >= 8) & (k8 == lcv);
        const bool tail = vE & ((nn == 15) | (kn != lcv));

        // pos update (w precomputed per node, gathered in phase A)
        const float wv = sW[el];
        float p0 = segscan(wv * sRel[3 * el + 0], m1, m2, m4, m8);
        float p1 = segscan(wv * sRel[3 * el + 1], m1, m2, m4, m8);
        float p2 = segscan(wv * sRel[3 * el + 2], m1, m2, m4, m8);
        if (tail && q == 0) {
          float* ap = sAccX + lcv * 68 + 64;  // pos acc lives in the pad
          lds_add(ap + 0, p0);
          lds_add(ap + 1, p1);
          lds_add(ap + 2, p2);
        }
#pragma unroll
        for (int it = 0; it < 4; ++it) {
          const float4 b2 = *(const float4*)(misc + 128 + it * 16 + q * 4);
          float v0 = segscan(acc2[m][it][0] + b2.x, m1, m2, m4, m8);
          float v1 = segscan(acc2[m][it][1] + b2.y, m1, m2, m4, m8);
          float v2 = segscan(acc2[m][it][2] + b2.z, m1, m2, m4, m8);
          float v3 = segscan(acc2[m][it][3] + b2.w, m1, m2, m4, m8);
          if (tail) {
            float* arow = sAccX + lcv * 68;
            const int i0 = it * 16 + q * 4;
            lds_add(arow + i0 + 0, v0);
            lds_add(arow + i0 + 1, v1);
            lds_add(arow + i0 + 2, v2);
            lds_add(arow + i0 + 3, v3);
          }
        }
      }
    }
    __syncthreads();
  }

  // ---- final coalesced stores (no global atomics)
  {
    const int n = base + (tid >> 2);
    if (n < NODES) {
      const int c0 = (tid & 3) * 16;
      float* orow = out + (size_t)n * 64 + c0;
      const float* arow = sAccX + (tid >> 2) * 68 + c0;
#pragma unroll
      for (int j = 0; j < 16; j += 4) *(float4*)(orow + j) = *(const float4*)(arow + j);
    }
    if (tid < 192) {
      const int idx = base * 3 + tid;
      if (idx < NODES * 3)
        out[(size_t)NODES * 64 + idx] = sAccX[(tid / 3) * 68 + 64 + (tid % 3)];
    }
  }
}

extern "C" void kernel_launch(void* const* d_in, const int* in_sizes, int n_in,
                              void* d_out, int out_size, void* d_ws, size_t ws_size,
                              hipStream_t stream) {
  (void)in_sizes; (void)n_in; (void)ws_size; (void)out_size;
  const float* x = (const float*)d_in[0];
  const float* pos = (const float*)d_in[1];
  const int* ei = (const int*)d_in[2];
  const float* Wx1 = (const float*)d_in[3];
  const float* bx1 = (const float*)d_in[4];
  const float* Wx2 = (const float*)d_in[5];
  const float* bx2 = (const float*)d_in[6];
  const float* Wp1 = (const float*)d_in[7];
  const float* bp1 = (const float*)d_in[8];
  const float* Wp2 = (const float*)d_in[9];
  const float* bp2 = (const float*)d_in[10];
  float* out = (float*)d_out;
  unsigned char* ws = (unsigned char*)d_ws;

  int* counts = (int*)(ws + WS_CNT);   // aliased with cursor (scan3 rewrites)
  int* cursor = (int*)(ws + WS_CNT);
  int* off = (int*)(ws + WS_OFF);
  int* tmp = (int*)(ws + WS_TMP);      // aliased with srec (dies before scatter)
  int* bsum = (int*)(ws + WS_BSUM);
  int* bsumx = (int*)(ws + WS_BSUMX);
  unsigned int* srec = (unsigned int*)(ws + WS_SREC);

  hipMemsetAsync(counts, 0, (size_t)NODES * sizeof(int), stream);
  prep_kernel<<<16, 256, 0, stream>>>(Wx1, Wx2, Wp1, bx1, bx2, bp1, Wp2, bp2, ws);
  wpos_kernel<<<NBW, 256, 0, stream>>>(x, pos, ws);
  const int eb = (EDGES + 255) / 256;
  hist_kernel<<<eb, 256, 0, stream>>>(ei, counts);
  scan1_kernel<<<SCB, 1024, 0, stream>>>(counts, tmp, bsum);
  scan2_kernel<<<1, 128, 0, stream>>>(bsum, bsumx);
  scan3_kernel<<<SCB, 1024, 0, stream>>>(counts, tmp, bsumx, off, cursor);
  scatter_kernel<<<eb, 256, 0, stream>>>(ei, cursor, srec);
  node_kernel<<<NBLK, 256, 0, stream>>>(x, ws, out);
}

// Round 4
// 456.864 us; speedup vs baseline: 3.1115x; 1.0238x over previous
//
#include <hip/hip_runtime.h>

#define EDGES 1000000
#define NODES 100000
#define ET 128   // edges per tile
#define NB 64    // nodes per block (node_kernel)
#define NBLK ((NODES + NB - 1) / NB)  // 1563
#define NBW ((NODES + 127) / 128)     // 782 wpos blocks

typedef short short8 __attribute__((ext_vector_type(8)));
typedef float floatx4 __attribute__((ext_vector_type(4)));
typedef unsigned int u32x2 __attribute__((ext_vector_type(2)));
typedef unsigned int u32x4 __attribute__((ext_vector_type(4)));

#define MFMA(a, b, c) __builtin_amdgcn_mfma_f32_16x16x32_bf16(a, b, c, 0, 0, 0)

// ws layout (bytes)
#define WS_WX1 0        // 32768: Wx1 bf16 frags
#define WS_WX2 32768    // 16384: Wx2 frags
#define WS_WP1 49152    // 16384: Wp1 frags
#define WS_MISC 65536   // 2048: biases etc (floats)
#define WS_OFF 68608    // off[100128] int = 400512 B (CSR offsets, padded)
#define WS_CNT 469504   // counts/cursor[100000] int = 400000 B (aliased)
#define WS_SREC 917504  // u32[EDGES] = 4 MB packed sorted records (lc<<17|r)
#define WS_POSW 8917504 // float4[NODES] = 1.6 MB {pos.xyz, w_pos} per node
// scan temporaries alias the srec region (they die before scatter writes srec):
#define WS_TMP WS_SREC                 // int[100352] inclusive per-block scans
#define WS_BSUM (WS_SREC + 401408)     // int[98] block sums

__device__ __forceinline__ unsigned short f2bf(float f) {
  union { float f; unsigned int u; } c;
  c.f = f;
  unsigned int u = c.u;
  u += 0x7fffu + ((u >> 16) & 1u);
  return (unsigned short)(u >> 16);
}

__device__ __forceinline__ unsigned int pack2bf(float lo, float hi) {
  return (unsigned int)f2bf(lo) | ((unsigned int)f2bf(hi) << 16);
}

// single-instruction RNE pack (same rounding as f2bf); no builtin on gfx950
__device__ __forceinline__ unsigned int cvtpk2bf(float lo, float hi) {
  unsigned int r;
  asm("v_cvt_pk_bf16_f32 %0, %1, %2" : "=v"(r) : "v"(lo), "v"(hi));
  return r;
}

__device__ __forceinline__ float fast_silu(float v) {
#if __has_builtin(__builtin_amdgcn_exp2f) && __has_builtin(__builtin_amdgcn_rcpf)
  float e = __builtin_amdgcn_exp2f(-1.44269504088896340736f * v);
  return v * __builtin_amdgcn_rcpf(1.0f + e);
#else
  return v / (1.0f + __expf(-v));
#endif
}

// DPP cross-lane within 16-lane rows. row_shr:N = lane i reads lane i-N.
// MUST be called unconditionally in straight-line code (convergent ops).
template <int CTRL>
__device__ __forceinline__ int dpp_i(int v) {
  return __builtin_amdgcn_update_dpp(0, v, CTRL, 0xf, 0xf, true);
}
template <int CTRL>
__device__ __forceinline__ float dpp_f(float v) {
  return __builtin_bit_cast(float, dpp_i<CTRL>(__builtin_bit_cast(int, v)));
}

// Segmented inclusive prefix-sum across nn (16-lane row), segments = runs of
// equal sorted keys; masks m1..m8 from unconditional key equality at d=1,2,4,8.
__device__ __forceinline__ float segscan(float v, bool m1, bool m2, bool m4, bool m8) {
  float t;
  t = dpp_f<0x111>(v); v += m1 ? t : 0.f;
  t = dpp_f<0x112>(v); v += m2 ? t : 0.f;
  t = dpp_f<0x114>(v); v += m4 ? t : 0.f;
  t = dpp_f<0x118>(v); v += m8 ? t : 0.f;
  return v;
}

__device__ __forceinline__ void lds_add(float* p, float v) {
  __hip_atomic_fetch_add(p, v, __ATOMIC_RELAXED, __HIP_MEMORY_SCOPE_WORKGROUP);
}

// prep also zero-inits counts (folds the old hipMemsetAsync launch in; hist
// runs after prep on the same stream)
__global__ __launch_bounds__(256) void prep_kernel(
    const float* __restrict__ Wx1, const float* __restrict__ Wx2,
    const float* __restrict__ Wp1, const float* __restrict__ bx1,
    const float* __restrict__ bx2, const float* __restrict__ bp1,
    const float* __restrict__ Wp2, const float* __restrict__ bp2,
    unsigned char* __restrict__ ws) {
  const int t = blockIdx.x * 256 + threadIdx.x;
  const int nthr = gridDim.x * 256;

  int* counts = (int*)(ws + WS_CNT);
  for (int i = t; i < NODES; i += nthr) counts[i] = 0;

  for (int task = t; task < 2048; task += nthr) {  // Wx1[0:128][0:128]
    const int n = task & 127;
    const int kb = task >> 7;
    const int k0 = kb << 3;
    unsigned int d[4];
#pragma unroll
    for (int i = 0; i < 4; ++i)
      d[i] = pack2bf(Wx1[(k0 + 2 * i) * 128 + n], Wx1[(k0 + 2 * i + 1) * 128 + n]);
    const int lane = ((kb & 3) << 4) | (n & 15);
    const int frag = ((kb >> 2) << 3) | (n >> 4);
    *(uint4*)(ws + WS_WX1 + ((size_t)(frag * 64 + lane) << 4)) =
        make_uint4(d[0], d[1], d[2], d[3]);
  }
  for (int task = t; task < 1024; task += nthr) {  // Wx2[0:128][0:64]
    const int n = task & 63;
    const int kb = task >> 6;
    const int k0 = kb << 3;
    unsigned int d[4];
#pragma unroll
    for (int i = 0; i < 4; ++i)
      d[i] = pack2bf(Wx2[(k0 + 2 * i) * 64 + n], Wx2[(k0 + 2 * i + 1) * 64 + n]);
    const int lane = ((kb & 3) << 4) | (n & 15);
    const int frag = ((kb >> 2) << 2) | (n >> 4);
    *(uint4*)(ws + WS_WX2 + ((size_t)(frag * 64 + lane) << 4)) =
        make_uint4(d[0], d[1], d[2], d[3]);
  }
  for (int task = t; task < 1024; task += nthr) {  // Wp1[0:64][0:128]
    const int n = task & 127;
    const int kb = task >> 7;
    const int k0 = kb << 3;
    unsigned int d[4];
#pragma unroll
    for (int i = 0; i < 4; ++i)
      d[i] = pack2bf(Wp1[(k0 + 2 * i) * 128 + n], Wp1[(k0 + 2 * i + 1) * 128 + n]);
    const int lane = ((kb & 3) << 4) | (n & 15);
    const int frag = ((kb >> 2) << 3) | (n >> 4);
    *(uint4*)(ws + WS_WP1 + ((size_t)(frag * 64 + lane) << 4)) =
        make_uint4(d[0], d[1], d[2], d[3]);
  }
  float* misc = (float*)(ws + WS_MISC);
  for (int i = t; i < 128; i += nthr) misc[i] = bx1[i];
  for (int i = t; i < 64; i += nthr) misc[128 + i] = bx2[i];
  for (int i = t; i < 128; i += nthr) misc[192 + i] = bp1[i];
  for (int i = t; i < 128; i += nthr) misc[320 + i] = Wp2[i];
  if (t == 0) misc[448] = bp2[0];
  for (int i = t; i < 128; i += nthr) misc[456 + i] = Wx1[128 * 128 + i];
}

// ---- per-NODE phi_pos precompute (R12) ----
__global__ __launch_bounds__(256) void wpos_kernel(
    const float* __restrict__ x, const float* __restrict__ pos,
    unsigned char* __restrict__ ws) {
  const uint4* wp1f = (const uint4*)(ws + WS_WP1);
  const float* misc = (const float*)(ws + WS_MISC);
  float* posw = (float*)(ws + WS_POSW);

  const int tid = threadIdx.x;
  const int lane = tid & 63;
  const int wave = tid >> 6;
  const int q = lane >> 4;
  const int nn = lane & 15;
  const int base = blockIdx.x * 128 + wave * 32;  // this wave: nodes base..base+31

  short8 bf[2][2];
#pragma unroll
  for (int m = 0; m < 2; ++m) {
    int node = base + m * 16 + nn;
    node = node < NODES ? node : NODES - 1;
#pragma unroll
    for (int kt = 0; kt < 2; ++kt) {
      const int k0 = kt * 32 + q * 8;
      const float4 a = *(const float4*)(x + (size_t)node * 64 + k0);
      const float4 b = *(const float4*)(x + (size_t)node * 64 + k0 + 4);
      u32x4 d;
      d[0] = cvtpk2bf(a.x, a.y);
      d[1] = cvtpk2bf(a.z, a.w);
      d[2] = cvtpk2bf(b.x, b.y);
      d[3] = cvtpk2bf(b.z, b.w);
      bf[m][kt] = __builtin_bit_cast(short8, d);
    }
  }

  const floatx4 fzero = {0.f, 0.f, 0.f, 0.f};
  floatx4 accp[2][8];
#pragma unroll
  for (int m = 0; m < 2; ++m)
#pragma unroll
    for (int j = 0; j < 8; ++j) accp[m][j] = fzero;
#pragma unroll 1
  for (int kt = 0; kt < 2; ++kt) {
#pragma unroll
    for (int jt = 0; jt < 8; ++jt) {
      const short8 a = __builtin_bit_cast(short8, wp1f[(kt * 8 + jt) * 64 + lane]);
      accp[0][jt] = MFMA(a, bf[0][kt], accp[0][jt]);
      accp[1][jt] = MFMA(a, bf[1][kt], accp[1][jt]);
    }
  }
#pragma unroll
  for (int m = 0; m < 2; ++m) {
    float s = 0.f;
#pragma unroll
    for (int jt = 0; jt < 8; ++jt) {
      const float4 bp = *(const float4*)(misc + 192 + jt * 16 + q * 4);
      const float4 wp = *(const float4*)(misc + 320 + jt * 16 + q * 4);
      s += fast_silu(accp[m][jt][0] + bp.x) * wp.x;
      s += fast_silu(accp[m][jt][1] + bp.y) * wp.y;
      s += fast_silu(accp[m][jt][2] + bp.z) * wp.z;
      s += fast_silu(accp[m][jt][3] + bp.w) * wp.w;
    }
    s += __shfl_xor(s, 16);
    s += __shfl_xor(s, 32);
    const int node = base + m * 16 + nn;
    if (q == 0 && node < NODES) {
      float4 o;
      o.x = pos[3 * node + 0];
      o.y = pos[3 * node + 1];
      o.z = pos[3 * node + 2];
      o.w = s + misc[448];
      *(float4*)(posw + 4 * (size_t)node) = o;
    }
  }
}

// ---- counting sort by col ----
__global__ __launch_bounds__(256) void hist_kernel(const int* __restrict__ ei,
                                                   int* __restrict__ counts) {
  const int t = blockIdx.x * 256 + threadIdx.x;
  if (t < EDGES) {
    int c = __builtin_nontemporal_load(ei + EDGES + t);
    c = (c < 0) ? 0 : ((c >= NODES) ? NODES - 1 : c);
    atomicAdd(&counts[c], 1);
  }
}

#define SCB 98  // blocks of 1024: 98*1024 = 100352 >= NODES+128

__global__ __launch_bounds__(1024) void scan1_kernel(const int* __restrict__ counts,
                                                     int* __restrict__ tmp,
                                                     int* __restrict__ bsum) {
  __shared__ int part[1024];
  const int t = threadIdx.x;
  const int i = blockIdx.x * 1024 + t;
  int v = (i < NODES) ? counts[i] : 0;
  part[t] = v;
  __syncthreads();
  for (int d = 1; d < 1024; d <<= 1) {
    int u = 0;
    if (t >= d) u = part[t - d];
    __syncthreads();
    if (t >= d) part[t] += u;
    __syncthreads();
  }
  tmp[i] = part[t];  // inclusive scan within block
  if (t == 1023) bsum[blockIdx.x] = part[1023];
}

// R13: scan2 merged in — each block re-scans the 98 block sums in LDS
// (tiny log-scan) and picks its exclusive prefix; kills one launch + bsumx.
__global__ __launch_bounds__(1024) void scan3_kernel(const int* __restrict__ counts,
                                                     const int* __restrict__ tmp,
                                                     const int* __restrict__ bsum,
                                                     int* __restrict__ off,
                                                     int* __restrict__ cursor) {
  __shared__ int sb[128];
  const int t = threadIdx.x;
  if (t < 128) sb[t] = (t < SCB) ? bsum[t] : 0;
  __syncthreads();
  for (int d = 1; d < 128; d <<= 1) {
    int u = 0;
    if (t >= d && t < 128) u = sb[t - d];
    __syncthreads();
    if (t >= d && t < 128) sb[t] += u;
    __syncthreads();
  }
  const int bx = (blockIdx.x == 0) ? 0 : sb[blockIdx.x - 1];  // exclusive
  const int i = blockIdx.x * 1024 + t;
  if (i < NODES) {
    const int cn = counts[i];  // read before cursor write (aliased with counts)
    const int o = bx + tmp[i] - cn;
    off[i] = o;
    cursor[i] = o;
  } else if (i < NODES + 128) {
    off[i] = EDGES;
  }
}

// R13: packed record — lc = c & 63 is exact (node_kernel block base is
// (c>>6)*64), r < 2^17. One u32 per edge: halves scatter writes + node reads.
__global__ __launch_bounds__(256) void scatter_kernel(const int* __restrict__ ei,
                                                      int* __restrict__ cursor,
                                                      unsigned int* __restrict__ srec) {
  const int t = blockIdx.x * 256 + threadIdx.x;
  if (t < EDGES) {
    int r = __builtin_nontemporal_load(ei + t);
    int c = __builtin_nontemporal_load(ei + EDGES + t);
    r = (r < 0) ? 0 : ((r >= NODES) ? NODES - 1 : r);
    c = (c < 0) ? 0 : ((c >= NODES) ? NODES - 1 : c);
    const int p = atomicAdd(&cursor[c], 1);
    __builtin_nontemporal_store(((unsigned)(c & 63) << 17) | (unsigned)r, srec + p);
  }
}

// ---- main: node-centric, zero global atomics, ZERO in-loop barriers ----
// R13 on the R12 skeleton:
// (a) wave-own metadata: each wave's lanes 0-31 prefetch + write the wave's
//     own 32 edge slots. Every in-loop LDS array access is now wave-private
//     (sFeat rows 8w..8w+7, sRC/sW/sRel/sDist slots 32w..32w+31); sAccX is
//     atomic-only. BOTH in-loop __syncthreads deleted — waves free-run,
//     DS-pipe program order covers own-wave write->read. This is R10's goal
//     at ~10 VGPR instead of 96 (which spilled).
// (b) packed srec u32 (lc<<17|r): phase-B metadata reads halve; lc needs no
//     clamp (6-bit field).
// (c) LDS 53760 -> 53248 B (sRowE+sLC+sW -> sRC+sW): back to 3 blocks/CU
//     (R12 accidentally dropped to 2).
// kt loops stay unroll(1) (anti-spill, r3-r5 lesson).
__global__ __launch_bounds__(256, 3) void node_kernel(
    const float* __restrict__ x, const unsigned char* __restrict__ ws,
    float* __restrict__ out) {
  __shared__ uint4 sFeat[2048];                    // 32 KB B-operand frags
  __shared__ __align__(16) float sAccX[NB * 68];   // 17 KB; cols 64..66 = pos acc
  __shared__ float sRel[ET * 3];                   // 1.5 KB
  __shared__ float sDist[ET];                      // 0.5 KB
  __shared__ float sW[ET];                         // 0.5 KB
  __shared__ unsigned int sRC[ET];                 // 0.5 KB packed (lc<<17|r)

  const int tid = threadIdx.x;
  const int lane = tid & 63;
  const int wave = tid >> 6;
  const int q = lane >> 4;
  const int nn = lane & 15;
  const int base = blockIdx.x * NB;
  const int et0 = wave * 2;
  const int W32 = wave * 32;

  const int* off = (const int*)(ws + WS_OFF);
  const unsigned int* srec = (const unsigned int*)(ws + WS_SREC);
  const uint4* wx1f = (const uint4*)(ws + WS_WX1);
  const uint4* wx2f = (const uint4*)(ws + WS_WX2);
  const float* misc = (const float*)(ws + WS_MISC);
  const float* posw = (const float*)(ws + WS_POSW);

  const int e0 = off[base];
  const int e1 = off[base + NB];

  // prologue prefetch: lanes 0-31 own edge slots W32+lane of tile 0
  unsigned int prec = 0;
  float4 pR = {0.f, 0.f, 0.f, 0.f}, pC = {0.f, 0.f, 0.f, 0.f};
  if (lane < 32) {
    int e = e0 + W32 + lane;
    e = e < EDGES ? e : EDGES - 1;
    prec = srec[e];
    const int r = (int)(prec & 0x1FFFF);
    int c = base + (int)(prec >> 17);
    c = c < NODES ? c : NODES - 1;  // clamped-invalid lanes on last block
    pR = *(const float4*)(posw + 4 * (size_t)r);
    pC = *(const float4*)(posw + 4 * (size_t)c);
  }

  for (int i = tid; i < NB * 68; i += 256) sAccX[i] = 0.f;
  __syncthreads();  // sAccX ready before any wave's first lds_add

  const floatx4 fzero = {0.f, 0.f, 0.f, 0.f};

#pragma unroll 1
  for (int t0 = e0; t0 < e1; t0 += ET) {
    // ---- phase A: wave-own metadata -> LDS (pure LDS writes, no barrier)
    if (lane < 32) {
      const int j = W32 + lane;
      const float r0 = pR.x - pC.x;
      const float r1 = pR.y - pC.y;
      const float r2 = pR.z - pC.z;
      sRC[j] = prec;
      sW[j] = pR.w;
      sRel[3 * j + 0] = r0;
      sRel[3 * j + 1] = r1;
      sRel[3 * j + 2] = r2;
      sDist[j] = r0 * r0 + r1 * r1 + r2 * r2;
    }

    // ---- prefetch next tile's srec (arrives during phase B)
    unsigned int rcN = 0;
    if (lane < 32) {
      int e = t0 + ET + W32 + lane;
      e = e < EDGES ? e : EDGES - 1;
      rcN = srec[e];
    }

    // ---- phase B: coalesced gathers, 16 lanes per node row; all 16 loads
    // of both halves batched in flight (no accumulators live here).
    {
      unsigned int rec8[8];
#pragma unroll
      for (int i = 0; i < 8; ++i)
        rec8[i] = sRC[W32 + i * 4 + (lane >> 4)];
      int nodeid[16];
#pragma unroll
      for (int i = 0; i < 8; ++i) {
        nodeid[i] = (int)(rec8[i] & 0x1FFFF);           // half 0: x[row]
        nodeid[8 + i] = base + (int)(rec8[i] >> 17);    // half 1: x[col]
      }
      float4 v[16];
#pragma unroll
      for (int i = 0; i < 16; ++i)
        v[i] = *(const float4*)(x + (size_t)nodeid[i] * 64 + (lane & 15) * 4);
#pragma unroll
      for (int i = 0; i < 16; ++i) {
        const int half = i >> 3;
        const int s = W32 + (i & 7) * 4 + (lane >> 4);
        const int kq = lane & 15;
        const int et = s >> 4;
        const int kt = (half << 1) | (kq >> 3);
        const int fl = (((kq >> 1) & 3) << 4) | (s & 15);
        u32x2 d;
        d[0] = cvtpk2bf(v[i].x, v[i].y);
        d[1] = cvtpk2bf(v[i].z, v[i].w);
        *((u32x2*)&sFeat[(et * 4 + kt) * 64 + fl] + (kq & 1)) = d;
      }
    }

    // ---- prefetch next tile's posw (rcN arrived during B; these float4
    // loads fly during GEMM1+GEMM2; ~10 VGPR live — metadata only)
    if (lane < 32) {
      prec = rcN;
      const int r = (int)(prec & 0x1FFFF);
      int c = base + (int)(prec >> 17);
      c = c < NODES ? c : NODES - 1;
      pR = *(const float4*)(posw + 4 * (size_t)r);
      pC = *(const float4*)(posw + 4 * (size_t)c);
    }

    // ---- GEMM1 (mm-paired) + epilogue 1
    {
      floatx4 acc1[2][8];
#pragma unroll
      for (int m = 0; m < 2; ++m)
#pragma unroll
        for (int j = 0; j < 8; ++j) acc1[m][j] = fzero;
#pragma unroll 1
      for (int kt = 0; kt < 4; ++kt) {
        const short8 b0 = __builtin_bit_cast(short8, sFeat[((et0 + 0) * 4 + kt) * 64 + lane]);
        const short8 b1 = __builtin_bit_cast(short8, sFeat[((et0 + 1) * 4 + kt) * 64 + lane]);
#pragma unroll
        for (int jt = 0; jt < 8; ++jt) {
          const short8 a = __builtin_bit_cast(short8, wx1f[(kt * 8 + jt) * 64 + lane]);
          acc1[0][jt] = MFMA(a, b0, acc1[0][jt]);
          acc1[1][jt] = MFMA(a, b1, acc1[1][jt]);
        }
      }
#pragma unroll
      for (int m = 0; m < 2; ++m) {
        const int etG = et0 + m;
        const float dist = sDist[etG * 16 + nn];
#pragma unroll
        for (int jt = 0; jt < 8; ++jt) {
          const float4 bx = *(const float4*)(misc + 0 + jt * 16 + q * 4);
          const float4 wd = *(const float4*)(misc + 456 + jt * 16 + q * 4);
          const unsigned int h01 = cvtpk2bf(fast_silu(acc1[m][jt][0] + bx.x + dist * wd.x),
                                            fast_silu(acc1[m][jt][1] + bx.y + dist * wd.y));
          const unsigned int h23 = cvtpk2bf(fast_silu(acc1[m][jt][2] + bx.z + dist * wd.z),
                                            fast_silu(acc1[m][jt][3] + bx.w + dist * wd.w));
          const int j0 = jt * 16 + q * 4;
          const int kt2 = j0 >> 5;
          const int lane2 = (((j0 & 31) >> 3) << 4) | nn;
          const int byteoff = (j0 & 7) << 1;
          uint2* dst = (uint2*)((char*)sFeat +
                                (((size_t)((etG * 4 + kt2) * 64 + lane2)) << 4) + byteoff);
          *dst = make_uint2(h01, h23);
        }
      }
    }

    // ---- GEMM2 (mm-paired) + merged segmented-scan scatter epilogue
    {
      floatx4 acc2[2][4];
#pragma unroll
      for (int m = 0; m < 2; ++m)
#pragma unroll
        for (int it = 0; it < 4; ++it) acc2[m][it] = fzero;
#pragma unroll 1
      for (int kt = 0; kt < 4; ++kt) {
        const short8 b0 = __builtin_bit_cast(short8, sFeat[((et0 + 0) * 4 + kt) * 64 + lane]);
        const short8 b1 = __builtin_bit_cast(short8, sFeat[((et0 + 1) * 4 + kt) * 64 + lane]);
#pragma unroll
        for (int it = 0; it < 4; ++it) {
          const short8 a = __builtin_bit_cast(short8, wx2f[(kt * 4 + it) * 64 + lane]);
          acc2[0][it] = MFMA(a, b0, acc2[0][it]);
          acc2[1][it] = MFMA(a, b1, acc2[1][it]);
        }
      }
#pragma unroll
      for (int m = 0; m < 2; ++m) {
        const int el = (et0 + m) * 16 + nn;
        const bool vE = (t0 + el) < e1;
        int lcv = (int)(sRC[el] >> 17);
        if (!vE) lcv = -1 - nn;  // singleton segments for invalid lanes
        // unconditional DPPs (convergent!) then bitwise combines:
        const int k1 = dpp_i<0x111>(lcv);
        const int k2 = dpp_i<0x112>(lcv);
        const int k4 = dpp_i<0x114>(lcv);
        const int k8 = dpp_i<0x118>(lcv);
        const int kn = dpp_i<0x101>(lcv);
        const bool m1 = (nn >= 1) & (k1 == lcv);
        const bool m2 = (nn >= 2) & (k2 == lcv);
        const bool m4 = (nn >= 4) & (k4 == lcv);
        const bool m8 = (nn >= 8) & (k8 == lcv);
        const bool tail = vE & ((nn == 15) | (kn != lcv));

        // pos update (w precomputed per node, gathered in phase A)
        const float wv = sW[el];
        float p0 = segscan(wv * sRel[3 * el + 0], m1, m2, m4, m8);
        float p1 = segscan(wv * sRel[3 * el + 1], m1, m2, m4, m8);
        float p2 = segscan(wv * sRel[3 * el + 2], m1, m2, m4, m8);
        if (tail && q == 0) {
          float* ap = sAccX + lcv * 68 + 64;  // pos acc lives in the pad
          lds_add(ap + 0, p0);
          lds_add(ap + 1, p1);
          lds_add(ap + 2, p2);
        }
#pragma unroll
        for (int it = 0; it < 4; ++it) {
          const float4 b2 = *(const float4*)(misc + 128 + it * 16 + q * 4);
          float v0 = segscan(acc2[m][it][0] + b2.x, m1, m2, m4, m8);
          float v1 = segscan(acc2[m][it][1] + b2.y, m1, m2, m4, m8);
          float v2 = segscan(acc2[m][it][2] + b2.z, m1, m2, m4, m8);
          float v3 = segscan(acc2[m][it][3] + b2.w, m1, m2, m4, m8);
          if (tail) {
            float* arow = sAccX + lcv * 68;
            const int i0 = it * 16 + q * 4;
            lds_add(arow + i0 + 0, v0);
            lds_add(arow + i0 + 1, v1);
            lds_add(arow + i0 + 2, v2);
            lds_add(arow + i0 + 3, v3);
          }
        }
      }
    }
    // no end-of-loop barrier: next phase A overwrites only wave-own slots,
    // ordered by the wave's in-order DS pipe.
  }
  __syncthreads();  // all waves' LDS-atomic accumulates done

  // ---- final coalesced stores (no global atomics)
  {
    const int n = base + (tid >> 2);
    if (n < NODES) {
      const int c0 = (tid & 3) * 16;
      float* orow = out + (size_t)n * 64 + c0;
      const float* arow = sAccX + (tid >> 2) * 68 + c0;
#pragma unroll
      for (int j = 0; j < 16; j += 4) *(float4*)(orow + j) = *(const float4*)(arow + j);
    }
    if (tid < 192) {
      const int idx = base * 3 + tid;
      if (idx < NODES * 3)
        out[(size_t)NODES * 64 + idx] = sAccX[(tid / 3) * 68 + 64 + (tid % 3)];
    }
  }
}

extern "C" void kernel_launch(void* const* d_in, const int* in_sizes, int n_in,
                              void* d_out, int out_size, void* d_ws, size_t ws_size,
                              hipStream_t stream) {
  (void)in_sizes; (void)n_in; (void)ws_size; (void)out_size;
  const float* x = (const float*)d_in[0];
  const float* pos = (const float*)d_in[1];
  const int* ei = (const int*)d_in[2];
  const float* Wx1 = (const float*)d_in[3];
  const float* bx1 = (const float*)d_in[4];
  const float* Wx2 = (const float*)d_in[5];
  const float* bx2 = (const float*)d_in[6];
  const float* Wp1 = (const float*)d_in[7];
  const float* bp1 = (const float*)d_in[8];
  const float* Wp2 = (const float*)d_in[9];
  const float* bp2 = (const float*)d_in[10];
  float* out = (float*)d_out;
  unsigned char* ws = (unsigned char*)d_ws;

  int* counts = (int*)(ws + WS_CNT);   // aliased with cursor (scan3 rewrites)
  int* cursor = (int*)(ws + WS_CNT);
  int* off = (int*)(ws + WS_OFF);
  int* tmp = (int*)(ws + WS_TMP);      // aliased with srec (dies before scatter)
  int* bsum = (int*)(ws + WS_BSUM);
  unsigned int* srec = (unsigned int*)(ws + WS_SREC);

  prep_kernel<<<16, 256, 0, stream>>>(Wx1, Wx2, Wp1, bx1, bx2, bp1, Wp2, bp2, ws);
  wpos_kernel<<<NBW, 256, 0, stream>>>(x, pos, ws);
  const int eb = (EDGES + 255) / 256;
  hist_kernel<<<eb, 256, 0, stream>>>(ei, counts);
  scan1_kernel<<<SCB, 1024, 0, stream>>>(counts, tmp, bsum);
  scan3_kernel<<<SCB, 1024, 0, stream>>>(counts, tmp, bsum, off, cursor);
  scatter_kernel<<<eb, 256, 0, stream>>>(ei, cursor, srec);
  node_kernel<<<NBLK, 256, 0, stream>>>(x, ws, out);
}